// Round 14
// baseline (1051.481 us; speedup 1.0000x reference)
//
#include <hip/hip_runtime.h>
#include <math.h>

#define NMS_THR 0.3f
#define NACC 8       // accumulator waves in k_scan
#define PROBE_REPS 8 // probe workload multiplier (visibility in top-5)

__device__ __forceinline__ float fmul(float a, float b){ return __fmul_rn(a,b); }
__device__ __forceinline__ float fadd(float a, float b){ return __fadd_rn(a,b); }
__device__ __forceinline__ float fsub(float a, float b){ return __fsub_rn(a,b); }

#define BAR_LDS() asm volatile("s_waitcnt lgkmcnt(0)\n\ts_barrier" ::: "memory")

__device__ __forceinline__ unsigned long long rdlane64(unsigned long long v, int a) {
    unsigned long long l = (unsigned int)__builtin_amdgcn_readlane((int)(unsigned int)v, a);
    unsigned long long h = (unsigned int)__builtin_amdgcn_readlane((int)(unsigned int)(v >> 32), a);
    return (h << 32) | l;
}
__device__ __forceinline__ unsigned long long rfl64(unsigned long long x){
    unsigned int lo = (unsigned int)__builtin_amdgcn_readfirstlane((int)(unsigned int)x);
    unsigned int hi = (unsigned int)__builtin_amdgcn_readfirstlane((int)(unsigned int)(x >> 32));
    return ((unsigned long long)hi << 32) | lo;
}
__device__ __forceinline__ unsigned long long waveOr64(unsigned long long v){
    for (int o = 32; o > 0; o >>= 1) v |= __shfl_xor(v, o);
    return v;
}

// K1: decode (unchanged)
__global__ __launch_bounds__(256) void k_decode(
    const float* __restrict__ prop, const float* __restrict__ reg,
    const float* __restrict__ clss, const float* __restrict__ stds,
    const int* __restrict__ imgsz,
    float* __restrict__ boxes, float* __restrict__ key,
    float* __restrict__ score, int* __restrict__ cls,
    int N, int C)
{
    int wid  = threadIdx.x >> 6;
    int lane = threadIdx.x & 63;
    int n = blockIdx.x * 4 + wid;
    if (n >= N) return;
    const float* row = clss + (long)n * C;
    float ninf = -__builtin_inff();
    float x0 = (lane < C)      ? row[lane]      : ninf;
    float x1 = (lane + 64 < C) ? row[lane + 64] : ninf;
    float m = fmaxf(x0, x1);
    for (int o = 32; o > 0; o >>= 1) m = fmaxf(m, __shfl_xor(m, o));
    float e0 = (lane < C)      ? expf(x0 - m) : 0.0f;
    float e1 = (lane + 64 < C) ? expf(x1 - m) : 0.0f;
    float s = e0 + e1;
    for (int o = 32; o > 0; o >>= 1) s += __shfl_xor(s, o);
    float bv; int bi;
    if (e0 >= e1) { bv = e0; bi = lane; } else { bv = e1; bi = lane + 64; }
    for (int o = 32; o > 0; o >>= 1) {
        float ov = __shfl_xor(bv, o);
        int   oi = __shfl_xor(bi, o);
        if (ov > bv || (ov == bv && oi < bi)) { bv = ov; bi = oi; }
    }
    if (lane == 0) {
        float sc = 1.0f / s;
        int   c  = bi;
        int   valid = (c != 0);
        float p0 = prop[n*4+0], p1 = prop[n*4+1], p2 = prop[n*4+2], p3 = prop[n*4+3];
        float w  = fsub(p2, p0), h = fsub(p3, p1);
        float cx = fadd(p0, fmul(0.5f, w));
        float cy = fadd(p1, fmul(0.5f, h));
        const float* rr = reg + (long)n * C * 4 + (long)c * 4;
        float t0 = fmul(rr[0], stds[0]);
        float t1 = fmul(rr[1], stds[1]);
        float t2 = fmul(rr[2], stds[2]);
        float t3 = fmul(rr[3], stds[3]);
        float px = fadd(cx, fmul(w, t0));
        float py = fadd(cy, fmul(h, t1));
        float pw = fmul(w, expf(t2));
        float ph = fmul(h, expf(t3));
        float hi = (float)(imgsz[0] - 1);
        float bx1 = fminf(fmaxf(fsub(px, fmul(0.5f, pw)), 0.0f), hi);
        float by1 = fminf(fmaxf(fsub(py, fmul(0.5f, ph)), 0.0f), hi);
        float bx2 = fminf(fmaxf(fadd(px, fmul(0.5f, pw)), 0.0f), hi);
        float by2 = fminf(fmaxf(fadd(py, fmul(0.5f, ph)), 0.0f), hi);
        boxes[n*4+0]=bx1; boxes[n*4+1]=by1; boxes[n*4+2]=bx2; boxes[n*4+3]=by2;
        score[n] = sc;
        cls[n]   = c;
        key[n]   = valid ? sc : ninf;
    }
}

// K2: rank (unchanged)
__global__ __launch_bounds__(256) void k_rank(
    const float* __restrict__ key, const float* __restrict__ boxes,
    float* __restrict__ boxesSorted, float* __restrict__ areaSorted,
    float* __restrict__ keySorted, int* __restrict__ rank,
    int* __restrict__ nValidPtr, int N)
{
    extern __shared__ float lkey[];
    __shared__ int part[256];
    int tid = threadIdx.x;
    for (int j = tid; j < N; j += 256) lkey[j] = key[j];
    __syncthreads();

    int i = blockIdx.x * 64 + (tid & 63);
    int s = tid >> 6;
    int Q = (N + 3) >> 2;
    int r_part = 0;
    if (i < N) {
        float ki = lkey[i];
        int j0 = s * Q, j1 = min(N, j0 + Q);
        for (int j = j0; j < j1; ++j) {
            float kj = lkey[j];
            r_part += (kj > ki) || (kj == ki && j < i);
        }
    }
    part[tid] = r_part;
    __syncthreads();

    if (tid < 64 && i < N) {
        int r = part[tid] + part[tid+64] + part[tid+128] + part[tid+192];
        float ki = lkey[i];
        rank[i] = r;
        float b0 = boxes[i*4+0], b1 = boxes[i*4+1], b2 = boxes[i*4+2], b3 = boxes[i*4+3];
        boxesSorted[r*4+0]=b0; boxesSorted[r*4+1]=b1; boxesSorted[r*4+2]=b2; boxesSorted[r*4+3]=b3;
        areaSorted[r] = fmul(fsub(b2,b0), fsub(b3,b1));
        keySorted[r]  = ki;
    }

    if (blockIdx.x == 0) {
        __syncthreads();
        float ninf = -__builtin_inff();
        int inv = 0;
        for (int j = tid; j < N; j += 256) inv += (lkey[j] == ninf);
        part[tid] = inv;
        __syncthreads();
        if (tid == 0) {
            int t = 0;
            for (int q = 0; q < 256; ++q) t += part[q];
            nValidPtr[0] = N - t;
        }
    }
}

// K3: mask (unchanged)
__global__ __launch_bounds__(256) void k_mask(
    const float* __restrict__ bs, const float* __restrict__ areas,
    const float* __restrict__ keySorted, unsigned long long* __restrict__ mask,
    unsigned long long* __restrict__ dq,
    int N, int W, int Wpad)
{
    int wid  = threadIdx.x >> 6;
    int lane = threadIdx.x & 63;
    int i = blockIdx.x * 4 + wid;
    if (i >= N) return;
    if (keySorted[i] == -__builtin_inff()) return;
    float ax1 = bs[i*4+0], ay1 = bs[i*4+1], ax2 = bs[i*4+2], ay2 = bs[i*4+3];
    float aa  = areas[i];
    int w0 = i >> 6;
    if (lane == 0) {
        dq[i*4+0] = 0ULL; dq[i*4+1] = 0ULL; dq[i*4+2] = 0ULL; dq[i*4+3] = 0ULL;
    }
    for (int w = w0; w < W; ++w) {
        int j = w*64 + lane;
        int bit = 0;
        if (j < N && j > i) {
            float bx1 = bs[j*4+0], by1 = bs[j*4+1], bx2 = bs[j*4+2], by2 = bs[j*4+3];
            float ba  = areas[j];
            float ix1 = fmaxf(ax1,bx1), iy1 = fmaxf(ay1,by1);
            float ix2 = fminf(ax2,bx2), iy2 = fminf(ay2,by2);
            float iw = fmaxf(fsub(ix2,ix1), 0.0f);
            float ih = fmaxf(fsub(iy2,iy1), 0.0f);
            float inter = fmul(iw, ih);
            float denom = fadd(fsub(fadd(aa, ba), inter), 1e-9f);
            float iou = inter / denom;
            bit = (iou > NMS_THR) ? 1 : 0;
        }
        unsigned long long bm = __ballot(bit);
        if (lane == 0) {
            mask[(long)i*Wpad + w] = bm;
            int d = w - w0;
            if (d < 4) dq[i*4+d] = bm;
        }
    }
}

// K4: production scan (R12 + recording), unchanged from R13.
__global__ __launch_bounds__((NACC+1)*64, 1) void k_scan(
    const unsigned long long* __restrict__ mask,
    const unsigned long long* __restrict__ dq,
    const int* __restrict__ nValidPtr,
    int* __restrict__ keepSorted,
    unsigned long long* __restrict__ incRec,
    unsigned long long* __restrict__ keepRec,
    int N, int W, int Wpad)
{
    __shared__ unsigned long long ldsPartA[NACC+1];
    __shared__ unsigned long long ldsPartB[NACC+1];
    __shared__ unsigned long long ldsKeepLo, ldsKeepHi;
    int tid  = threadIdx.x;
    int wid  = tid >> 6;
    int lane = tid & 63;
    for (int i = tid; i < N; i += (NACC+1)*64) keepSorted[i] = 0;
    if (tid <= NACC) { ldsPartA[tid] = 0ULL; ldsPartB[tid] = 0ULL; }
    if (tid == 0) { ldsKeepLo = 0ULL; ldsKeepHi = 0ULL; }
    __syncthreads();

    int nValid  = __builtin_amdgcn_readfirstlane(nValidPtr[0]);
    int nChunks = (nValid + 127) >> 7;

    unsigned long long A0=0,A1=0,A2=0,A3=0,B0=0,B1=0,B2=0,B3=0;
    unsigned long long sacc_prevA = 0ULL, sacc_prevB = 0ULL;
    if (wid == 0 && nChunks > 0) {
        int rA = lane, rB = 64 + lane;
        if (rA < N) {
            ulonglong2 a01 = *(const ulonglong2*)(dq + (size_t)rA*4);
            ulonglong2 a23 = *(const ulonglong2*)(dq + (size_t)rA*4 + 2);
            A0=a01.x; A1=a01.y; A2=a23.x; A3=a23.y;
        }
        if (rB < N) {
            ulonglong2 b01 = *(const ulonglong2*)(dq + (size_t)rB*4);
            ulonglong2 b23 = *(const ulonglong2*)(dq + (size_t)rB*4 + 2);
            B0=b01.x; B1=b01.y; B2=b23.x; B3=b23.y;
        }
    }
    unsigned long long accx = 0ULL, accy = 0ULL;
    bool accWave = (wid >= 1);
    int  accIdx  = wid - 1;
    bool laneok  = (2*lane + 1 < Wpad);

    for (int c = 0; c < nChunks; ++c) {
        int base = c << 7;
        if (wid == 0) {
            unsigned long long nA0=0,nA1=0,nA2=0,nA3=0,nB0=0,nB1=0,nB2=0,nB3=0;
            if (c + 1 < nChunks) {
                int rA = base + 128 + lane, rB = base + 192 + lane;
                if (rA < N) {
                    ulonglong2 a01 = *(const ulonglong2*)(dq + (size_t)rA*4);
                    ulonglong2 a23 = *(const ulonglong2*)(dq + (size_t)rA*4 + 2);
                    nA0=a01.x; nA1=a01.y; nA2=a23.x; nA3=a23.y;
                }
                if (rB < N) {
                    ulonglong2 b01 = *(const ulonglong2*)(dq + (size_t)rB*4);
                    ulonglong2 b23 = *(const ulonglong2*)(dq + (size_t)rB*4 + 2);
                    nB0=b01.x; nB1=b01.y; nB2=b23.x; nB3=b23.y;
                }
            }

            unsigned long long pA = sacc_prevA, pB = sacc_prevB;
#pragma unroll
            for (int k = 1; k <= NACC; ++k) { pA |= ldsPartA[k]; pB |= ldsPartB[k]; }
            unsigned long long incLo = rfl64(pA), incHi = rfl64(pB);
            if (lane == 0) { incRec[2*c] = incLo; incRec[2*c+1] = incHi; }
            int nv  = nValid - base;
            unsigned long long validLo = (nv >= 64) ? ~0ULL : ((1ULL << nv) - 1ULL);
            int nv2 = nv - 64;
            unsigned long long validHi = (nv2 >= 64) ? ~0ULL
                                        : (nv2 <= 0 ? 0ULL : ((1ULL << nv2) - 1ULL));
            unsigned long long candLo = validLo & ~incLo;
            unsigned long long candHi = validHi & ~incHi;
            unsigned long long keepLo = 0ULL, keepHi = 0ULL;

            unsigned long long mHiAcc = 0ULL;
            while (candLo) {
                unsigned long long t = candLo;
                int a0 = __builtin_ctzll(t); t &= t - 1;
                int a1 = t ? __builtin_ctzll(t) : a0; t &= t - 1;
                int a2 = t ? __builtin_ctzll(t) : a0; t &= t - 1;
                int a3 = t ? __builtin_ctzll(t) : a0;
                unsigned long long m0 = rdlane64(A0, a0), m1 = rdlane64(A0, a1);
                unsigned long long m2 = rdlane64(A0, a2), m3 = rdlane64(A0, a3);
                unsigned long long n0 = rdlane64(A1, a0), n1 = rdlane64(A1, a1);
                unsigned long long n2 = rdlane64(A1, a2), n3 = rdlane64(A1, a3);
                unsigned long long rem  = m0 | (1ULL << a0);
                unsigned long long kept = 1ULL << a0;
                unsigned long long hi   = n0;
                unsigned long long b;
                b = 1ULL << a1; if (!(rem & b)) { rem |= m1 | b; kept |= b; hi |= n1; }
                b = 1ULL << a2; if (!(rem & b)) { rem |= m2 | b; kept |= b; hi |= n2; }
                b = 1ULL << a3; if (!(rem & b)) { rem |= m3 | b; kept |= b; hi |= n3; }
                keepLo |= kept; mHiAcc |= hi;
                candLo &= ~rem;
            }
            candHi &= ~mHiAcc;
            while (candHi) {
                unsigned long long t = candHi;
                int a0 = __builtin_ctzll(t); t &= t - 1;
                int a1 = t ? __builtin_ctzll(t) : a0; t &= t - 1;
                int a2 = t ? __builtin_ctzll(t) : a0; t &= t - 1;
                int a3 = t ? __builtin_ctzll(t) : a0;
                unsigned long long m0 = rdlane64(B0, a0), m1 = rdlane64(B0, a1);
                unsigned long long m2 = rdlane64(B0, a2), m3 = rdlane64(B0, a3);
                unsigned long long rem  = m0 | (1ULL << a0);
                unsigned long long kept = 1ULL << a0;
                unsigned long long b;
                b = 1ULL << a1; if (!(rem & b)) { rem |= m1 | b; kept |= b; }
                b = 1ULL << a2; if (!(rem & b)) { rem |= m2 | b; kept |= b; }
                b = 1ULL << a3; if (!(rem & b)) { rem |= m3 | b; kept |= b; }
                keepHi |= kept;
                candHi &= ~rem;
            }
            {
                unsigned long long kL = (keepLo >> lane) & 1ULL;
                unsigned long long kH = (keepHi >> lane) & 1ULL;
                unsigned long long selA = (kL ? A2 : 0ULL) | (kH ? B1 : 0ULL);
                unsigned long long selB = (kL ? A3 : 0ULL) | (kH ? B2 : 0ULL);
                sacc_prevA = waveOr64(selA);
                sacc_prevB = waveOr64(selB);
            }
            if (lane == 0) {
                ldsKeepLo = keepLo; ldsKeepHi = keepHi;
                keepRec[2*c] = keepLo; keepRec[2*c+1] = keepHi;
            }
            if (base + lane < N)      keepSorted[base + lane]      = (int)((keepLo >> lane) & 1ULL);
            if (base + 64 + lane < N) keepSorted[base + 64 + lane] = (int)((keepHi >> lane) & 1ULL);
            A0=nA0; A1=nA1; A2=nA2; A3=nA3; B0=nB0; B1=nB1; B2=nB2; B3=nB3;
        }
        BAR_LDS();
        unsigned long long kLo = ldsKeepLo;
        unsigned long long kHi = ldsKeepHi;
        if (accWave && laneok && lane == c + 1) {
            ldsPartA[wid] = accx;
            ldsPartB[wid] = accy;
        }
        BAR_LDS();
        if (accWave && laneok) {
            unsigned int myb = (accIdx < 4)
                ? (unsigned int)((kLo >> (16*accIdx)) & 0xFFFFULL)
                : (unsigned int)((kHi >> (16*(accIdx-4))) & 0xFFFFULL);
            if (myb) {
                const unsigned long long* mb =
                    mask + (size_t)(base + 16*accIdx) * Wpad + 2*lane;
                unsigned int b = myb;
                int a0 = __builtin_ctz(b); b &= b - 1;
                int a1=-1,a2=-1,a3=-1,a4=-1,a5=-1,a6=-1,a7=-1;
                if (b) { a1 = __builtin_ctz(b); b &= b - 1; }
                if (b) { a2 = __builtin_ctz(b); b &= b - 1; }
                if (b) { a3 = __builtin_ctz(b); b &= b - 1; }
                if (b) { a4 = __builtin_ctz(b); b &= b - 1; }
                if (b) { a5 = __builtin_ctz(b); b &= b - 1; }
                if (b) { a6 = __builtin_ctz(b); b &= b - 1; }
                if (b) { a7 = __builtin_ctz(b); b &= b - 1; }
                ulonglong2 v0 = {0,0}, v1 = {0,0}, v2 = {0,0}, v3 = {0,0};
                ulonglong2 v4 = {0,0}, v5 = {0,0}, v6 = {0,0}, v7 = {0,0};
                v0 = *(const ulonglong2*)(mb + (size_t)a0 * Wpad);
                if (a1 >= 0) v1 = *(const ulonglong2*)(mb + (size_t)a1 * Wpad);
                if (a2 >= 0) v2 = *(const ulonglong2*)(mb + (size_t)a2 * Wpad);
                if (a3 >= 0) v3 = *(const ulonglong2*)(mb + (size_t)a3 * Wpad);
                if (a4 >= 0) v4 = *(const ulonglong2*)(mb + (size_t)a4 * Wpad);
                if (a5 >= 0) v5 = *(const ulonglong2*)(mb + (size_t)a5 * Wpad);
                if (a6 >= 0) v6 = *(const ulonglong2*)(mb + (size_t)a6 * Wpad);
                if (a7 >= 0) v7 = *(const ulonglong2*)(mb + (size_t)a7 * Wpad);
                accx |= ((v0.x|v1.x)|(v2.x|v3.x)) | ((v4.x|v5.x)|(v6.x|v7.x));
                accy |= ((v0.y|v1.y)|(v2.y|v3.y)) | ((v4.y|v5.y)|(v6.y|v7.y));
                while (b) {
                    int a = __builtin_ctz(b); b &= b - 1;
                    ulonglong2 v = *(const ulonglong2*)(mb + (size_t)a * Wpad);
                    accx |= v.x; accy |= v.y;
                }
            }
        }
    }
}

// K5: output (unchanged)
__global__ __launch_bounds__(256) void k_out(
    const float* __restrict__ boxes, const float* __restrict__ score,
    const int* __restrict__ cls, const int* __restrict__ rank,
    const int* __restrict__ keepSorted,
    float* __restrict__ out, int N)
{
    int n = blockIdx.x * blockDim.x + threadIdx.x;
    if (n >= N) return;
    int k = keepSorted[rank[n]];
    float m = (float)k;
    out[n*4+0] = boxes[n*4+0]*m;
    out[n*4+1] = boxes[n*4+1]*m;
    out[n*4+2] = boxes[n*4+2]*m;
    out[n*4+3] = boxes[n*4+3]*m;
    out[(long)N*4 + n] = score[n]*m;
    out[(long)N*5 + n] = (float)(cls[n] * k);
}

// PROBE 1: resolver-only replay, looped PROBE_REPS times.
__global__ __launch_bounds__(64, 1) void k_probe_res(
    const unsigned long long* __restrict__ dq,
    const unsigned long long* __restrict__ incRec,
    const int* __restrict__ nValidPtr,
    unsigned long long* __restrict__ scratchKeep,
    int N)
{
    int lane = threadIdx.x;
    int nValid  = __builtin_amdgcn_readfirstlane(nValidPtr[0]);
    int nChunks = (nValid + 127) >> 7;
    unsigned long long sink = 0ULL;

    for (int rep = 0; rep < PROBE_REPS; ++rep) {
        unsigned long long A0=0,A1=0,A2=0,A3=0,B0=0,B1=0,B2=0,B3=0;
        if (nChunks > 0) {
            int rA = lane, rB = 64 + lane;
            if (rA < N) {
                ulonglong2 a01 = *(const ulonglong2*)(dq + (size_t)rA*4);
                ulonglong2 a23 = *(const ulonglong2*)(dq + (size_t)rA*4 + 2);
                A0=a01.x; A1=a01.y; A2=a23.x; A3=a23.y;
            }
            if (rB < N) {
                ulonglong2 b01 = *(const ulonglong2*)(dq + (size_t)rB*4);
                ulonglong2 b23 = *(const ulonglong2*)(dq + (size_t)rB*4 + 2);
                B0=b01.x; B1=b01.y; B2=b23.x; B3=b23.y;
            }
        }
        for (int c = 0; c < nChunks; ++c) {
            int base = c << 7;
            unsigned long long nA0=0,nA1=0,nA2=0,nA3=0,nB0=0,nB1=0,nB2=0,nB3=0;
            if (c + 1 < nChunks) {
                int rA = base + 128 + lane, rB = base + 192 + lane;
                if (rA < N) {
                    ulonglong2 a01 = *(const ulonglong2*)(dq + (size_t)rA*4);
                    ulonglong2 a23 = *(const ulonglong2*)(dq + (size_t)rA*4 + 2);
                    nA0=a01.x; nA1=a01.y; nA2=a23.x; nA3=a23.y;
                }
                if (rB < N) {
                    ulonglong2 b01 = *(const ulonglong2*)(dq + (size_t)rB*4);
                    ulonglong2 b23 = *(const ulonglong2*)(dq + (size_t)rB*4 + 2);
                    nB0=b01.x; nB1=b01.y; nB2=b23.x; nB3=b23.y;
                }
            }
            unsigned long long incLo = rfl64(incRec[2*c]);
            unsigned long long incHi = rfl64(incRec[2*c+1]);
            int nv  = nValid - base;
            unsigned long long validLo = (nv >= 64) ? ~0ULL : ((1ULL << nv) - 1ULL);
            int nv2 = nv - 64;
            unsigned long long validHi = (nv2 >= 64) ? ~0ULL
                                        : (nv2 <= 0 ? 0ULL : ((1ULL << nv2) - 1ULL));
            unsigned long long candLo = validLo & ~incLo;
            unsigned long long candHi = validHi & ~incHi;
            unsigned long long keepLo = 0ULL, keepHi = 0ULL;

            unsigned long long mHiAcc = 0ULL;
            while (candLo) {
                unsigned long long t = candLo;
                int a0 = __builtin_ctzll(t); t &= t - 1;
                int a1 = t ? __builtin_ctzll(t) : a0; t &= t - 1;
                int a2 = t ? __builtin_ctzll(t) : a0; t &= t - 1;
                int a3 = t ? __builtin_ctzll(t) : a0;
                unsigned long long m0 = rdlane64(A0, a0), m1 = rdlane64(A0, a1);
                unsigned long long m2 = rdlane64(A0, a2), m3 = rdlane64(A0, a3);
                unsigned long long n0 = rdlane64(A1, a0), n1 = rdlane64(A1, a1);
                unsigned long long n2 = rdlane64(A1, a2), n3 = rdlane64(A1, a3);
                unsigned long long rem  = m0 | (1ULL << a0);
                unsigned long long kept = 1ULL << a0;
                unsigned long long hi   = n0;
                unsigned long long b;
                b = 1ULL << a1; if (!(rem & b)) { rem |= m1 | b; kept |= b; hi |= n1; }
                b = 1ULL << a2; if (!(rem & b)) { rem |= m2 | b; kept |= b; hi |= n2; }
                b = 1ULL << a3; if (!(rem & b)) { rem |= m3 | b; kept |= b; hi |= n3; }
                keepLo |= kept; mHiAcc |= hi;
                candLo &= ~rem;
            }
            candHi &= ~mHiAcc;
            while (candHi) {
                unsigned long long t = candHi;
                int a0 = __builtin_ctzll(t); t &= t - 1;
                int a1 = t ? __builtin_ctzll(t) : a0; t &= t - 1;
                int a2 = t ? __builtin_ctzll(t) : a0; t &= t - 1;
                int a3 = t ? __builtin_ctzll(t) : a0;
                unsigned long long m0 = rdlane64(B0, a0), m1 = rdlane64(B0, a1);
                unsigned long long m2 = rdlane64(B0, a2), m3 = rdlane64(B0, a3);
                unsigned long long rem  = m0 | (1ULL << a0);
                unsigned long long kept = 1ULL << a0;
                unsigned long long b;
                b = 1ULL << a1; if (!(rem & b)) { rem |= m1 | b; kept |= b; }
                b = 1ULL << a2; if (!(rem & b)) { rem |= m2 | b; kept |= b; }
                b = 1ULL << a3; if (!(rem & b)) { rem |= m3 | b; kept |= b; }
                keepHi |= kept;
                candHi &= ~rem;
            }
            {
                unsigned long long kL = (keepLo >> lane) & 1ULL;
                unsigned long long kH = (keepHi >> lane) & 1ULL;
                unsigned long long selA = (kL ? A2 : 0ULL) | (kH ? B1 : 0ULL);
                unsigned long long selB = (kL ? A3 : 0ULL) | (kH ? B2 : 0ULL);
                sink ^= waveOr64(selA) ^ waveOr64(selB);
            }
            sink ^= keepLo ^ keepHi;
            A0=nA0; A1=nA1; A2=nA2; A3=nA3; B0=nB0; B1=nB1; B2=nB2; B3=nB3;
        }
        if (lane == 0) scratchKeep[rep] = sink;   // keep live per rep
    }
}

// PROBE 2: barrier+accumulator side, looped PROBE_REPS times.
__global__ __launch_bounds__((NACC+1)*64, 1) void k_probe_acc(
    const unsigned long long* __restrict__ mask,
    const unsigned long long* __restrict__ keepRec,
    const int* __restrict__ nValidPtr,
    unsigned long long* __restrict__ scratchAcc,
    int N, int W, int Wpad)
{
    __shared__ unsigned long long ldsPartA[NACC+1];
    __shared__ unsigned long long ldsPartB[NACC+1];
    __shared__ unsigned long long ldsKeepLo, ldsKeepHi;
    int tid  = threadIdx.x;
    int wid  = tid >> 6;
    int lane = tid & 63;
    int nValid  = __builtin_amdgcn_readfirstlane(nValidPtr[0]);
    int nChunks = (nValid + 127) >> 7;

    unsigned long long accx = 0ULL, accy = 0ULL;
    bool accWave = (wid >= 1);
    int  accIdx  = wid - 1;
    bool laneok  = (2*lane + 1 < Wpad);

    for (int rep = 0; rep < PROBE_REPS; ++rep) {
        if (tid <= NACC) { ldsPartA[tid] = 0ULL; ldsPartB[tid] = 0ULL; }
        if (tid == 0) { ldsKeepLo = 0ULL; ldsKeepHi = 0ULL; }
        __syncthreads();

        unsigned long long curLo = 0ULL, curHi = 0ULL;
        if (wid == 0 && nChunks > 0) { curLo = keepRec[0]; curHi = keepRec[1]; }

        for (int c = 0; c < nChunks; ++c) {
            int base = c << 7;
            if (wid == 0) {
                unsigned long long nLo = 0ULL, nHi = 0ULL;
                if (c + 1 < nChunks) { nLo = keepRec[2*c+2]; nHi = keepRec[2*c+3]; }
                unsigned long long pA = 0ULL, pB = 0ULL;
#pragma unroll
                for (int k = 1; k <= NACC; ++k) { pA |= ldsPartA[k]; pB |= ldsPartB[k]; }
                if (lane == 0) {
                    ldsKeepLo = curLo; ldsKeepHi = curHi;
                    scratchAcc[126] = pA ^ pB;
                }
                curLo = nLo; curHi = nHi;
            }
            BAR_LDS();
            unsigned long long kLo = ldsKeepLo;
            unsigned long long kHi = ldsKeepHi;
            if (accWave && laneok && lane == c + 1) {
                ldsPartA[wid] = accx;
                ldsPartB[wid] = accy;
            }
            BAR_LDS();
            if (accWave && laneok) {
                unsigned int myb = (accIdx < 4)
                    ? (unsigned int)((kLo >> (16*accIdx)) & 0xFFFFULL)
                    : (unsigned int)((kHi >> (16*(accIdx-4))) & 0xFFFFULL);
                if (myb) {
                    const unsigned long long* mb =
                        mask + (size_t)(base + 16*accIdx) * Wpad + 2*lane;
                    unsigned int b = myb;
                    int a0 = __builtin_ctz(b); b &= b - 1;
                    int a1=-1,a2=-1,a3=-1,a4=-1,a5=-1,a6=-1,a7=-1;
                    if (b) { a1 = __builtin_ctz(b); b &= b - 1; }
                    if (b) { a2 = __builtin_ctz(b); b &= b - 1; }
                    if (b) { a3 = __builtin_ctz(b); b &= b - 1; }
                    if (b) { a4 = __builtin_ctz(b); b &= b - 1; }
                    if (b) { a5 = __builtin_ctz(b); b &= b - 1; }
                    if (b) { a6 = __builtin_ctz(b); b &= b - 1; }
                    if (b) { a7 = __builtin_ctz(b); b &= b - 1; }
                    ulonglong2 v0 = {0,0}, v1 = {0,0}, v2 = {0,0}, v3 = {0,0};
                    ulonglong2 v4 = {0,0}, v5 = {0,0}, v6 = {0,0}, v7 = {0,0};
                    v0 = *(const ulonglong2*)(mb + (size_t)a0 * Wpad);
                    if (a1 >= 0) v1 = *(const ulonglong2*)(mb + (size_t)a1 * Wpad);
                    if (a2 >= 0) v2 = *(const ulonglong2*)(mb + (size_t)a2 * Wpad);
                    if (a3 >= 0) v3 = *(const ulonglong2*)(mb + (size_t)a3 * Wpad);
                    if (a4 >= 0) v4 = *(const ulonglong2*)(mb + (size_t)a4 * Wpad);
                    if (a5 >= 0) v5 = *(const ulonglong2*)(mb + (size_t)a5 * Wpad);
                    if (a6 >= 0) v6 = *(const ulonglong2*)(mb + (size_t)a6 * Wpad);
                    if (a7 >= 0) v7 = *(const ulonglong2*)(mb + (size_t)a7 * Wpad);
                    accx |= ((v0.x|v1.x)|(v2.x|v3.x)) | ((v4.x|v5.x)|(v6.x|v7.x));
                    accy |= ((v0.y|v1.y)|(v2.y|v3.y)) | ((v4.y|v5.y)|(v6.y|v7.y));
                    while (b) {
                        int a = __builtin_ctz(b); b &= b - 1;
                        ulonglong2 v = *(const ulonglong2*)(mb + (size_t)a * Wpad);
                        accx |= v.x; accy |= v.y;
                    }
                }
            }
        }
        if (accWave) scratchAcc[wid*64 + (lane & 1)] = accx ^ accy ^ (unsigned long long)rep;
    }
}

extern "C" void kernel_launch(void* const* d_in, const int* in_sizes, int n_in,
                              void* d_out, int out_size, void* d_ws, size_t ws_size,
                              hipStream_t stream) {
    const float* prop = (const float*)d_in[0];
    const float* reg  = (const float*)d_in[1];
    const float* clss = (const float*)d_in[2];
    const float* stds = (const float*)d_in[3];
    const int*   img  = (const int*)d_in[4];

    int N = in_sizes[0] / 4;
    int C = in_sizes[2] / N;
    int W = (N + 63) / 64;
    int Wpad = (W + 1) & ~1;

    char* ws = (char*)d_ws;
    size_t off = 0;
    float* boxes       = (float*)(ws + off); off += (size_t)N*4*sizeof(float);
    float* key         = (float*)(ws + off); off += (size_t)N*sizeof(float);
    float* score       = (float*)(ws + off); off += (size_t)N*sizeof(float);
    int*   cls         = (int*)  (ws + off); off += (size_t)N*sizeof(int);
    int*   rank        = (int*)  (ws + off); off += (size_t)N*sizeof(int);
    float* boxesSorted = (float*)(ws + off); off += (size_t)N*4*sizeof(float);
    float* areaSorted  = (float*)(ws + off); off += (size_t)N*sizeof(float);
    float* keySorted   = (float*)(ws + off); off += (size_t)N*sizeof(float);
    int*   keepSorted  = (int*)  (ws + off); off += (size_t)N*sizeof(int);
    int*   nValid      = (int*)  (ws + off); off += sizeof(int);
    off = (off + 31) & ~(size_t)31;
    unsigned long long* dq    = (unsigned long long*)(ws + off);
    off += (size_t)N * 4 * sizeof(unsigned long long);
    unsigned long long* mask  = (unsigned long long*)(ws + off);
    off += (size_t)N * Wpad * sizeof(unsigned long long);
    unsigned long long* incRec     = (unsigned long long*)(ws + off); off += 128 * sizeof(unsigned long long);
    unsigned long long* keepRec    = (unsigned long long*)(ws + off); off += 128 * sizeof(unsigned long long);
    unsigned long long* scratchKeep= (unsigned long long*)(ws + off); off += 128 * sizeof(unsigned long long);
    unsigned long long* scratchAcc = (unsigned long long*)(ws + off); off += 1024 * sizeof(unsigned long long);
    (void)ws_size; (void)out_size; (void)n_in;

    int rowBlocks  = (N + 3) / 4;
    int thrBlocks  = (N + 255) / 256;
    int rankBlocks = (N + 63) / 64;

    k_decode<<<rowBlocks, 256, 0, stream>>>(prop, reg, clss, stds, img,
                                            boxes, key, score, cls, N, C);
    k_rank<<<rankBlocks, 256, (size_t)N*sizeof(float), stream>>>(key, boxes,
                                            boxesSorted, areaSorted, keySorted, rank, nValid, N);
    k_mask<<<rowBlocks, 256, 0, stream>>>(boxesSorted, areaSorted, keySorted,
                                          mask, dq, N, W, Wpad);
    k_scan<<<1, (NACC+1)*64, 0, stream>>>(mask, dq, nValid, keepSorted,
                                          incRec, keepRec, N, W, Wpad);
    k_out<<<thrBlocks, 256, 0, stream>>>(boxes, score, cls, rank, keepSorted,
                                         (float*)d_out, N);
    // diagnostic probes, looped x8 for top-5 visibility
    k_probe_res<<<1, 64, 0, stream>>>(dq, incRec, nValid, scratchKeep, N);
    k_probe_acc<<<1, (NACC+1)*64, 0, stream>>>(mask, keepRec, nValid, scratchAcc, N, W, Wpad);
}

// Round 15
// 215.611 us; speedup vs baseline: 4.8768x; 4.8768x over previous
//
#include <hip/hip_runtime.h>
#include <math.h>

#define NMS_THR 0.3f
#define NACC 8   // accumulator waves in k_scan (block = (1+NACC)*64 threads)

__device__ __forceinline__ float fmul(float a, float b){ return __fmul_rn(a,b); }
__device__ __forceinline__ float fadd(float a, float b){ return __fadd_rn(a,b); }
__device__ __forceinline__ float fsub(float a, float b){ return __fsub_rn(a,b); }

// Raw barrier: LDS ordering only — does NOT drain vmcnt.
#define BAR_LDS() asm volatile("s_waitcnt lgkmcnt(0)\n\ts_barrier" ::: "memory")

__device__ __forceinline__ unsigned long long rfl64(unsigned long long x){
    unsigned int lo = (unsigned int)__builtin_amdgcn_readfirstlane((int)(unsigned int)x);
    unsigned int hi = (unsigned int)__builtin_amdgcn_readfirstlane((int)(unsigned int)(x >> 32));
    return ((unsigned long long)hi << 32) | lo;
}

// 32-row greedy sub-phase, pure-SALU chain + pipelined aggregate readlanes.
// cand: SGPR candidate bits (32 rows). laneoff: lane base of these rows in the
// v* registers. vc: chain word (suppression of these 32 rows). vg1..vg7:
// aggregate words OR-accumulated over kept rows. Exact greedy: processes rows
// in increasing index; suppression masks only have bits for later rows.
__device__ __forceinline__ void sub_resolve(
    unsigned &cand, unsigned laneoff,
    unsigned vc, unsigned vg1, unsigned vg2, unsigned vg3,
    unsigned vg4, unsigned vg5, unsigned vg6, unsigned vg7,
    unsigned &k, unsigned &g1, unsigned &g2, unsigned &g3,
    unsigned &g4, unsigned &g5, unsigned &g6, unsigned &g7)
{
    unsigned a, al, bit, d, t1, t2, t3, t4;
    asm volatile(
        "s_mov_b32 %[k], 0\n\t"
        "s_mov_b32 %[g1], 0\n\t"
        "s_mov_b32 %[g2], 0\n\t"
        "s_mov_b32 %[g3], 0\n\t"
        "s_mov_b32 %[g4], 0\n\t"
        "s_mov_b32 %[g5], 0\n\t"
        "s_mov_b32 %[g6], 0\n\t"
        "s_mov_b32 %[g7], 0\n\t"
        "s_cmp_lg_u32 %[cand], 0\n\t"
        "s_cbranch_scc0 2f\n\t"
        "1:\n\t"
        "s_ff1_i32_b32 %[a], %[cand]\n\t"
        "s_add_i32 %[al], %[a], %[lo]\n\t"
        "v_readlane_b32 %[t1], %[vg1], %[al]\n\t"
        "v_readlane_b32 %[t2], %[vg2], %[al]\n\t"
        "v_readlane_b32 %[t3], %[vg3], %[al]\n\t"
        "v_readlane_b32 %[t4], %[vg4], %[al]\n\t"
        "s_lshl_b32 %[bit], 1, %[a]\n\t"
        "s_or_b32 %[g1], %[g1], %[t1]\n\t"
        "s_or_b32 %[g2], %[g2], %[t2]\n\t"
        "v_readlane_b32 %[t1], %[vg5], %[al]\n\t"
        "v_readlane_b32 %[t2], %[vg6], %[al]\n\t"
        "s_or_b32 %[g3], %[g3], %[t3]\n\t"
        "s_or_b32 %[g4], %[g4], %[t4]\n\t"
        "v_readlane_b32 %[t3], %[vg7], %[al]\n\t"
        "v_readlane_b32 %[d], %[vc], %[al]\n\t"
        "s_or_b32 %[g5], %[g5], %[t1]\n\t"
        "s_or_b32 %[g6], %[g6], %[t2]\n\t"
        "s_or_b32 %[k], %[k], %[bit]\n\t"
        "s_or_b32 %[g7], %[g7], %[t3]\n\t"
        "s_or_b32 %[d], %[d], %[bit]\n\t"
        "s_andn2_b32 %[cand], %[cand], %[d]\n\t"
        "s_cmp_lg_u32 %[cand], 0\n\t"
        "s_cbranch_scc1 1b\n\t"
        "2:\n\t"
        : [k]"=&s"(k), [g1]"=&s"(g1), [g2]"=&s"(g2), [g3]"=&s"(g3),
          [g4]"=&s"(g4), [g5]"=&s"(g5), [g6]"=&s"(g6), [g7]"=&s"(g7),
          [a]"=&s"(a), [al]"=&s"(al), [bit]"=&s"(bit), [d]"=&s"(d),
          [t1]"=&s"(t1), [t2]"=&s"(t2), [t3]"=&s"(t3), [t4]"=&s"(t4),
          [cand]"+s"(cand)
        : [lo]"s"(laneoff),
          [vc]"v"(vc), [vg1]"v"(vg1), [vg2]"v"(vg2), [vg3]"v"(vg3),
          [vg4]"v"(vg4), [vg5]"v"(vg5), [vg6]"v"(vg6), [vg7]"v"(vg7));
}

// K1: per-row softmax max/sum + argmax + per-class regression decode.
__global__ __launch_bounds__(256) void k_decode(
    const float* __restrict__ prop, const float* __restrict__ reg,
    const float* __restrict__ clss, const float* __restrict__ stds,
    const int* __restrict__ imgsz,
    float* __restrict__ boxes, float* __restrict__ key,
    float* __restrict__ score, int* __restrict__ cls,
    int N, int C)
{
    int wid  = threadIdx.x >> 6;
    int lane = threadIdx.x & 63;
    int n = blockIdx.x * 4 + wid;
    if (n >= N) return;
    const float* row = clss + (long)n * C;
    float ninf = -__builtin_inff();
    float x0 = (lane < C)      ? row[lane]      : ninf;
    float x1 = (lane + 64 < C) ? row[lane + 64] : ninf;
    float m = fmaxf(x0, x1);
    for (int o = 32; o > 0; o >>= 1) m = fmaxf(m, __shfl_xor(m, o));
    float e0 = (lane < C)      ? expf(x0 - m) : 0.0f;
    float e1 = (lane + 64 < C) ? expf(x1 - m) : 0.0f;
    float s = e0 + e1;
    for (int o = 32; o > 0; o >>= 1) s += __shfl_xor(s, o);
    float bv; int bi;
    if (e0 >= e1) { bv = e0; bi = lane; } else { bv = e1; bi = lane + 64; }
    for (int o = 32; o > 0; o >>= 1) {
        float ov = __shfl_xor(bv, o);
        int   oi = __shfl_xor(bi, o);
        if (ov > bv || (ov == bv && oi < bi)) { bv = ov; bi = oi; }
    }
    if (lane == 0) {
        float sc = 1.0f / s;
        int   c  = bi;
        int   valid = (c != 0);
        float p0 = prop[n*4+0], p1 = prop[n*4+1], p2 = prop[n*4+2], p3 = prop[n*4+3];
        float w  = fsub(p2, p0), h = fsub(p3, p1);
        float cx = fadd(p0, fmul(0.5f, w));
        float cy = fadd(p1, fmul(0.5f, h));
        const float* rr = reg + (long)n * C * 4 + (long)c * 4;
        float t0 = fmul(rr[0], stds[0]);
        float t1 = fmul(rr[1], stds[1]);
        float t2 = fmul(rr[2], stds[2]);
        float t3 = fmul(rr[3], stds[3]);
        float px = fadd(cx, fmul(w, t0));
        float py = fadd(cy, fmul(h, t1));
        float pw = fmul(w, expf(t2));
        float ph = fmul(h, expf(t3));
        float hi = (float)(imgsz[0] - 1);
        float bx1 = fminf(fmaxf(fsub(px, fmul(0.5f, pw)), 0.0f), hi);
        float by1 = fminf(fmaxf(fsub(py, fmul(0.5f, ph)), 0.0f), hi);
        float bx2 = fminf(fmaxf(fadd(px, fmul(0.5f, pw)), 0.0f), hi);
        float by2 = fminf(fmaxf(fadd(py, fmul(0.5f, ph)), 0.0f), hi);
        boxes[n*4+0]=bx1; boxes[n*4+1]=by1; boxes[n*4+2]=bx2; boxes[n*4+3]=by2;
        score[n] = sc;
        cls[n]   = c;
        key[n]   = valid ? sc : ninf;
    }
}

// K2: stable descending rank sort + nValid.
__global__ __launch_bounds__(256) void k_rank(
    const float* __restrict__ key, const float* __restrict__ boxes,
    float* __restrict__ boxesSorted, float* __restrict__ areaSorted,
    float* __restrict__ keySorted, int* __restrict__ rank,
    int* __restrict__ nValidPtr, int N)
{
    extern __shared__ float lkey[];
    __shared__ int part[256];
    int tid = threadIdx.x;
    for (int j = tid; j < N; j += 256) lkey[j] = key[j];
    __syncthreads();

    int i = blockIdx.x * 64 + (tid & 63);
    int s = tid >> 6;
    int Q = (N + 3) >> 2;
    int r_part = 0;
    if (i < N) {
        float ki = lkey[i];
        int j0 = s * Q, j1 = min(N, j0 + Q);
        for (int j = j0; j < j1; ++j) {
            float kj = lkey[j];
            r_part += (kj > ki) || (kj == ki && j < i);
        }
    }
    part[tid] = r_part;
    __syncthreads();

    if (tid < 64 && i < N) {
        int r = part[tid] + part[tid+64] + part[tid+128] + part[tid+192];
        float ki = lkey[i];
        rank[i] = r;
        float b0 = boxes[i*4+0], b1 = boxes[i*4+1], b2 = boxes[i*4+2], b3 = boxes[i*4+3];
        boxesSorted[r*4+0]=b0; boxesSorted[r*4+1]=b1; boxesSorted[r*4+2]=b2; boxesSorted[r*4+3]=b3;
        areaSorted[r] = fmul(fsub(b2,b0), fsub(b3,b1));
        keySorted[r]  = ki;
    }

    if (blockIdx.x == 0) {
        __syncthreads();
        float ninf = -__builtin_inff();
        int inv = 0;
        for (int j = tid; j < N; j += 256) inv += (lkey[j] == ninf);
        part[tid] = inv;
        __syncthreads();
        if (tid == 0) {
            int t = 0;
            for (int q = 0; q < 256; ++q) t += part[q];
            nValidPtr[0] = N - t;
        }
    }
}

// K3: suppression bitmask, row-major padded; dq[i*4+d] = word (i>>6)+d of row i.
__global__ __launch_bounds__(256) void k_mask(
    const float* __restrict__ bs, const float* __restrict__ areas,
    const float* __restrict__ keySorted, unsigned long long* __restrict__ mask,
    unsigned long long* __restrict__ dq,
    int N, int W, int Wpad)
{
    int wid  = threadIdx.x >> 6;
    int lane = threadIdx.x & 63;
    int i = blockIdx.x * 4 + wid;
    if (i >= N) return;
    if (keySorted[i] == -__builtin_inff()) return;
    float ax1 = bs[i*4+0], ay1 = bs[i*4+1], ax2 = bs[i*4+2], ay2 = bs[i*4+3];
    float aa  = areas[i];
    int w0 = i >> 6;
    if (lane == 0) {
        dq[i*4+0] = 0ULL; dq[i*4+1] = 0ULL; dq[i*4+2] = 0ULL; dq[i*4+3] = 0ULL;
    }
    for (int w = w0; w < W; ++w) {
        int j = w*64 + lane;
        int bit = 0;
        if (j < N && j > i) {
            float bx1 = bs[j*4+0], by1 = bs[j*4+1], bx2 = bs[j*4+2], by2 = bs[j*4+3];
            float ba  = areas[j];
            float ix1 = fmaxf(ax1,bx1), iy1 = fmaxf(ay1,by1);
            float ix2 = fminf(ax2,bx2), iy2 = fminf(ay2,by2);
            float iw = fmaxf(fsub(ix2,ix1), 0.0f);
            float ih = fmaxf(fsub(iy2,iy1), 0.0f);
            float inter = fmul(iw, ih);
            float denom = fadd(fsub(fadd(aa, ba), inter), 1e-9f);
            float iou = inter / denom;
            bit = (iou > NMS_THR) ? 1 : 0;
        }
        unsigned long long bm = __ballot(bit);
        if (lane == 0) {
            mask[(long)i*Wpad + w] = bm;
            int d = w - w0;
            if (d < 4) dq[i*4+d] = bm;
        }
    }
}

// K4: wave-specialized greedy scan, 128-row chunks. Resolver: pure-SALU asm
// resolve (4x 32-row sub-phases, s_ff1 + v_readlane(SGPR idx) + s_andn2; all
// aggregates accumulated in-loop). Acc waves: 16-bit deal slices, 8 named
// ulonglong2 loads, ldsPart publish (R12).
__global__ __launch_bounds__((NACC+1)*64, 1) void k_scan(
    const unsigned long long* __restrict__ mask,
    const unsigned long long* __restrict__ dq,
    const int* __restrict__ nValidPtr,
    int* __restrict__ keepSorted, int N, int W, int Wpad)
{
    __shared__ unsigned long long ldsPartA[NACC+1];
    __shared__ unsigned long long ldsPartB[NACC+1];
    __shared__ unsigned long long ldsKeepLo, ldsKeepHi;
    int tid  = threadIdx.x;
    int wid  = tid >> 6;
    int lane = tid & 63;
    for (int i = tid; i < N; i += (NACC+1)*64) keepSorted[i] = 0;
    if (tid <= NACC) { ldsPartA[tid] = 0ULL; ldsPartB[tid] = 0ULL; }
    if (tid == 0) { ldsKeepLo = 0ULL; ldsKeepHi = 0ULL; }
    __syncthreads();

    int nValid  = __builtin_amdgcn_readfirstlane(nValidPtr[0]);
    int nChunks = (nValid + 127) >> 7;

    unsigned long long A0=0,A1=0,A2=0,A3=0,B0=0,B1=0,B2=0,B3=0;
    unsigned long long sacc_prevA = 0ULL, sacc_prevB = 0ULL;
    if (wid == 0 && nChunks > 0) {
        int rA = lane, rB = 64 + lane;
        if (rA < N) {
            ulonglong2 a01 = *(const ulonglong2*)(dq + (size_t)rA*4);
            ulonglong2 a23 = *(const ulonglong2*)(dq + (size_t)rA*4 + 2);
            A0=a01.x; A1=a01.y; A2=a23.x; A3=a23.y;
        }
        if (rB < N) {
            ulonglong2 b01 = *(const ulonglong2*)(dq + (size_t)rB*4);
            ulonglong2 b23 = *(const ulonglong2*)(dq + (size_t)rB*4 + 2);
            B0=b01.x; B1=b01.y; B2=b23.x; B3=b23.y;
        }
    }
    unsigned long long accx = 0ULL, accy = 0ULL;
    bool accWave = (wid >= 1);
    int  accIdx  = wid - 1;
    bool laneok  = (2*lane + 1 < Wpad);

    for (int c = 0; c < nChunks; ++c) {
        int base = c << 7;
        if (wid == 0) {
            // prefetch next chunk's quads (vmem stays in flight across BAR_LDS)
            unsigned long long nA0=0,nA1=0,nA2=0,nA3=0,nB0=0,nB1=0,nB2=0,nB3=0;
            if (c + 1 < nChunks) {
                int rA = base + 128 + lane, rB = base + 192 + lane;
                if (rA < N) {
                    ulonglong2 a01 = *(const ulonglong2*)(dq + (size_t)rA*4);
                    ulonglong2 a23 = *(const ulonglong2*)(dq + (size_t)rA*4 + 2);
                    nA0=a01.x; nA1=a01.y; nA2=a23.x; nA3=a23.y;
                }
                if (rB < N) {
                    ulonglong2 b01 = *(const ulonglong2*)(dq + (size_t)rB*4);
                    ulonglong2 b23 = *(const ulonglong2*)(dq + (size_t)rB*4 + 2);
                    nB0=b01.x; nB1=b01.y; nB2=b23.x; nB3=b23.y;
                }
            }

            unsigned long long pA = sacc_prevA, pB = sacc_prevB;
#pragma unroll
            for (int k = 1; k <= NACC; ++k) { pA |= ldsPartA[k]; pB |= ldsPartB[k]; }
            unsigned long long incLo = rfl64(pA), incHi = rfl64(pB);
            int nv  = nValid - base;
            unsigned long long validLo = (nv >= 64) ? ~0ULL : ((1ULL << nv) - 1ULL);
            int nv2 = nv - 64;
            unsigned long long validHi = (nv2 >= 64) ? ~0ULL
                                        : (nv2 <= 0 ? 0ULL : ((1ULL << nv2) - 1ULL));
            unsigned long long candLo = validLo & ~incLo;
            unsigned long long candHi = validHi & ~incHi;

            // per-lane VGPR halves
            unsigned vA0lo=(unsigned)A0, vA0hi=(unsigned)(A0>>32);
            unsigned vA1lo=(unsigned)A1, vA1hi=(unsigned)(A1>>32);
            unsigned vA2lo=(unsigned)A2, vA2hi=(unsigned)(A2>>32);
            unsigned vA3lo=(unsigned)A3, vA3hi=(unsigned)(A3>>32);
            unsigned vB0lo=(unsigned)B0, vB0hi=(unsigned)(B0>>32);
            unsigned vB1lo=(unsigned)B1, vB1hi=(unsigned)(B1>>32);
            unsigned vB2lo=(unsigned)B2, vB2hi=(unsigned)(B2>>32);

            unsigned c0=(unsigned)candLo, c1=(unsigned)(candLo>>32);
            unsigned c2=(unsigned)candHi, c3=(unsigned)(candHi>>32);

            // 1a: rows base+0..31. aggs: A0hi, A1lo, A1hi, A2lo, A2hi, A3lo, A3hi
            unsigned k0,x1,x2,x3,x4,x5,x6,x7;
            sub_resolve(c0, 0u, vA0lo, vA0hi, vA1lo, vA1hi, vA2lo, vA2hi, vA3lo, vA3hi,
                        k0, x1,x2,x3,x4,x5,x6,x7);
            // 1b: rows base+32..63 (lanes 32-63). aggs: A1lo,A1hi,A2lo,A2hi,A3lo,A3hi
            c1 &= ~x1;
            unsigned k1,y1,y2,y3,y4,y5,y6,y7;
            sub_resolve(c1, 32u, vA0hi, vA1lo, vA1hi, vA2lo, vA2hi, vA3lo, vA3hi, vA0lo,
                        k1, y1,y2,y3,y4,y5,y6,y7);
            // mHi: phase-1 keeps' suppression of rows base+64..127
            c2 &= ~(x2 | y1);
            c3 &= ~(x3 | y2);
            // 2a: rows base+64..95. aggs: B0hi, B1lo, B1hi, B2lo, B2hi
            unsigned k2,z1,z2,z3,z4,z5,z6,z7;
            sub_resolve(c2, 0u, vB0lo, vB0hi, vB1lo, vB1hi, vB2lo, vB2hi, vB0lo, vB0lo,
                        k2, z1,z2,z3,z4,z5,z6,z7);
            // 2b: rows base+96..127 (lanes 32-63). aggs: B1lo, B1hi, B2lo, B2hi
            c3 &= ~z1;
            unsigned k3,w1,w2,w3,w4,w5,w6,w7;
            sub_resolve(c3, 32u, vB0hi, vB1lo, vB1hi, vB2lo, vB2hi, vB0lo, vB0lo, vB0lo,
                        k3, w1,w2,w3,w4,w5,w6,w7);
            (void)y7; (void)z6; (void)z7; (void)w5; (void)w6; (void)w7;

            unsigned long long keepLo = ((unsigned long long)k1 << 32) | k0;
            unsigned long long keepHi = ((unsigned long long)k3 << 32) | k2;
            // sacc word 2c+2: A2 over phase-1 keeps | B1 over phase-2 keeps
            unsigned sAlo = x4|y3|z2|w1, sAhi = x5|y4|z3|w2;
            // sacc word 2c+3: A3 | B2
            unsigned sBlo = x6|y5|z4|w3, sBhi = x7|y6|z5|w4;
            sacc_prevA = ((unsigned long long)sAhi << 32) | sAlo;
            sacc_prevB = ((unsigned long long)sBhi << 32) | sBlo;

            if (lane == 0) { ldsKeepLo = keepLo; ldsKeepHi = keepHi; }
            if (base + lane < N)      keepSorted[base + lane]      = (int)((keepLo >> lane) & 1ULL);
            if (base + 64 + lane < N) keepSorted[base + 64 + lane] = (int)((keepHi >> lane) & 1ULL);
            A0=nA0; A1=nA1; A2=nA2; A3=nA3; B0=nB0; B1=nB1; B2=nB2; B3=nB3;
        }
        BAR_LDS();                             // barrier A
        unsigned long long kLo = ldsKeepLo;
        unsigned long long kHi = ldsKeepHi;
        if (accWave && laneok && lane == c + 1) {  // publish words 2c+2, 2c+3
            ldsPartA[wid] = accx;
            ldsPartB[wid] = accy;
        }
        BAR_LDS();                             // barrier B
        if (accWave && laneok) {
            unsigned int myb = (accIdx < 4)
                ? (unsigned int)((kLo >> (16*accIdx)) & 0xFFFFULL)
                : (unsigned int)((kHi >> (16*(accIdx-4))) & 0xFFFFULL);
            if (myb) {
                const unsigned long long* mb =
                    mask + (size_t)(base + 16*accIdx) * Wpad + 2*lane;
                unsigned int b = myb;
                int a0 = __builtin_ctz(b); b &= b - 1;
                int a1=-1,a2=-1,a3=-1,a4=-1,a5=-1,a6=-1,a7=-1;
                if (b) { a1 = __builtin_ctz(b); b &= b - 1; }
                if (b) { a2 = __builtin_ctz(b); b &= b - 1; }
                if (b) { a3 = __builtin_ctz(b); b &= b - 1; }
                if (b) { a4 = __builtin_ctz(b); b &= b - 1; }
                if (b) { a5 = __builtin_ctz(b); b &= b - 1; }
                if (b) { a6 = __builtin_ctz(b); b &= b - 1; }
                if (b) { a7 = __builtin_ctz(b); b &= b - 1; }
                ulonglong2 v0 = {0,0}, v1 = {0,0}, v2 = {0,0}, v3 = {0,0};
                ulonglong2 v4 = {0,0}, v5 = {0,0}, v6 = {0,0}, v7 = {0,0};
                v0 = *(const ulonglong2*)(mb + (size_t)a0 * Wpad);
                if (a1 >= 0) v1 = *(const ulonglong2*)(mb + (size_t)a1 * Wpad);
                if (a2 >= 0) v2 = *(const ulonglong2*)(mb + (size_t)a2 * Wpad);
                if (a3 >= 0) v3 = *(const ulonglong2*)(mb + (size_t)a3 * Wpad);
                if (a4 >= 0) v4 = *(const ulonglong2*)(mb + (size_t)a4 * Wpad);
                if (a5 >= 0) v5 = *(const ulonglong2*)(mb + (size_t)a5 * Wpad);
                if (a6 >= 0) v6 = *(const ulonglong2*)(mb + (size_t)a6 * Wpad);
                if (a7 >= 0) v7 = *(const ulonglong2*)(mb + (size_t)a7 * Wpad);
                accx |= ((v0.x|v1.x)|(v2.x|v3.x)) | ((v4.x|v5.x)|(v6.x|v7.x));
                accy |= ((v0.y|v1.y)|(v2.y|v3.y)) | ((v4.y|v5.y)|(v6.y|v7.y));
                while (b) {
                    int a = __builtin_ctz(b); b &= b - 1;
                    ulonglong2 v = *(const ulonglong2*)(mb + (size_t)a * Wpad);
                    accx |= v.x; accy |= v.y;
                }
            }
        }
    }
}

// K5: write outputs in original order: boxes*m, score*m, float(cls*keep).
__global__ __launch_bounds__(256) void k_out(
    const float* __restrict__ boxes, const float* __restrict__ score,
    const int* __restrict__ cls, const int* __restrict__ rank,
    const int* __restrict__ keepSorted,
    float* __restrict__ out, int N)
{
    int n = blockIdx.x * blockDim.x + threadIdx.x;
    if (n >= N) return;
    int k = keepSorted[rank[n]];
    float m = (float)k;
    out[n*4+0] = boxes[n*4+0]*m;
    out[n*4+1] = boxes[n*4+1]*m;
    out[n*4+2] = boxes[n*4+2]*m;
    out[n*4+3] = boxes[n*4+3]*m;
    out[(long)N*4 + n] = score[n]*m;
    out[(long)N*5 + n] = (float)(cls[n] * k);
}

extern "C" void kernel_launch(void* const* d_in, const int* in_sizes, int n_in,
                              void* d_out, int out_size, void* d_ws, size_t ws_size,
                              hipStream_t stream) {
    const float* prop = (const float*)d_in[0];
    const float* reg  = (const float*)d_in[1];
    const float* clss = (const float*)d_in[2];
    const float* stds = (const float*)d_in[3];
    const int*   img  = (const int*)d_in[4];

    int N = in_sizes[0] / 4;
    int C = in_sizes[2] / N;
    int W = (N + 63) / 64;
    int Wpad = (W + 1) & ~1;

    char* ws = (char*)d_ws;
    size_t off = 0;
    float* boxes       = (float*)(ws + off); off += (size_t)N*4*sizeof(float);
    float* key         = (float*)(ws + off); off += (size_t)N*sizeof(float);
    float* score       = (float*)(ws + off); off += (size_t)N*sizeof(float);
    int*   cls         = (int*)  (ws + off); off += (size_t)N*sizeof(int);
    int*   rank        = (int*)  (ws + off); off += (size_t)N*sizeof(int);
    float* boxesSorted = (float*)(ws + off); off += (size_t)N*4*sizeof(float);
    float* areaSorted  = (float*)(ws + off); off += (size_t)N*sizeof(float);
    float* keySorted   = (float*)(ws + off); off += (size_t)N*sizeof(float);
    int*   keepSorted  = (int*)  (ws + off); off += (size_t)N*sizeof(int);
    int*   nValid      = (int*)  (ws + off); off += sizeof(int);
    off = (off + 31) & ~(size_t)31;
    unsigned long long* dq    = (unsigned long long*)(ws + off);
    off += (size_t)N * 4 * sizeof(unsigned long long);
    unsigned long long* mask  = (unsigned long long*)(ws + off);
    off += (size_t)N * Wpad * sizeof(unsigned long long);
    (void)ws_size; (void)out_size; (void)n_in;

    int rowBlocks  = (N + 3) / 4;
    int thrBlocks  = (N + 255) / 256;
    int rankBlocks = (N + 63) / 64;

    k_decode<<<rowBlocks, 256, 0, stream>>>(prop, reg, clss, stds, img,
                                            boxes, key, score, cls, N, C);
    k_rank<<<rankBlocks, 256, (size_t)N*sizeof(float), stream>>>(key, boxes,
                                            boxesSorted, areaSorted, keySorted, rank, nValid, N);
    k_mask<<<rowBlocks, 256, 0, stream>>>(boxesSorted, areaSorted, keySorted,
                                          mask, dq, N, W, Wpad);
    k_scan<<<1, (NACC+1)*64, 0, stream>>>(mask, dq, nValid, keepSorted, N, W, Wpad);
    k_out<<<thrBlocks, 256, 0, stream>>>(boxes, score, cls, rank, keepSorted,
                                         (float*)d_out, N);
}

// Round 16
// 180.984 us; speedup vs baseline: 5.8098x; 1.1913x over previous
//
#include <hip/hip_runtime.h>
#include <math.h>

#define NMS_THR 0.3f
#define NACC 8   // accumulator waves in k_scan (block = (1+NACC)*64 threads)

__device__ __forceinline__ float fmul(float a, float b){ return __fmul_rn(a,b); }
__device__ __forceinline__ float fadd(float a, float b){ return __fadd_rn(a,b); }
__device__ __forceinline__ float fsub(float a, float b){ return __fsub_rn(a,b); }

// Raw barrier: LDS ordering only — does NOT drain vmcnt.
#define BAR_LDS() asm volatile("s_waitcnt lgkmcnt(0)\n\ts_barrier" ::: "memory")

__device__ __forceinline__ unsigned long long rfl64(unsigned long long x){
    unsigned int lo = (unsigned int)__builtin_amdgcn_readfirstlane((int)(unsigned int)x);
    unsigned int hi = (unsigned int)__builtin_amdgcn_readfirstlane((int)(unsigned int)(x >> 32));
    return ((unsigned long long)hi << 32) | lo;
}
__device__ __forceinline__ unsigned long long waveOr64(unsigned long long v){
    for (int o = 32; o > 0; o >>= 1) v |= __shfl_xor(v, o);
    return v;
}

// K1: per-row softmax max/sum + argmax + per-class regression decode.
__global__ __launch_bounds__(256) void k_decode(
    const float* __restrict__ prop, const float* __restrict__ reg,
    const float* __restrict__ clss, const float* __restrict__ stds,
    const int* __restrict__ imgsz,
    float* __restrict__ boxes, float* __restrict__ key,
    float* __restrict__ score, int* __restrict__ cls,
    int N, int C)
{
    int wid  = threadIdx.x >> 6;
    int lane = threadIdx.x & 63;
    int n = blockIdx.x * 4 + wid;
    if (n >= N) return;
    const float* row = clss + (long)n * C;
    float ninf = -__builtin_inff();
    float x0 = (lane < C)      ? row[lane]      : ninf;
    float x1 = (lane + 64 < C) ? row[lane + 64] : ninf;
    float m = fmaxf(x0, x1);
    for (int o = 32; o > 0; o >>= 1) m = fmaxf(m, __shfl_xor(m, o));
    float e0 = (lane < C)      ? expf(x0 - m) : 0.0f;
    float e1 = (lane + 64 < C) ? expf(x1 - m) : 0.0f;
    float s = e0 + e1;
    for (int o = 32; o > 0; o >>= 1) s += __shfl_xor(s, o);
    float bv; int bi;
    if (e0 >= e1) { bv = e0; bi = lane; } else { bv = e1; bi = lane + 64; }
    for (int o = 32; o > 0; o >>= 1) {
        float ov = __shfl_xor(bv, o);
        int   oi = __shfl_xor(bi, o);
        if (ov > bv || (ov == bv && oi < bi)) { bv = ov; bi = oi; }
    }
    if (lane == 0) {
        float sc = 1.0f / s;
        int   c  = bi;
        int   valid = (c != 0);
        float p0 = prop[n*4+0], p1 = prop[n*4+1], p2 = prop[n*4+2], p3 = prop[n*4+3];
        float w  = fsub(p2, p0), h = fsub(p3, p1);
        float cx = fadd(p0, fmul(0.5f, w));
        float cy = fadd(p1, fmul(0.5f, h));
        const float* rr = reg + (long)n * C * 4 + (long)c * 4;
        float t0 = fmul(rr[0], stds[0]);
        float t1 = fmul(rr[1], stds[1]);
        float t2 = fmul(rr[2], stds[2]);
        float t3 = fmul(rr[3], stds[3]);
        float px = fadd(cx, fmul(w, t0));
        float py = fadd(cy, fmul(h, t1));
        float pw = fmul(w, expf(t2));
        float ph = fmul(h, expf(t3));
        float hi = (float)(imgsz[0] - 1);
        float bx1 = fminf(fmaxf(fsub(px, fmul(0.5f, pw)), 0.0f), hi);
        float by1 = fminf(fmaxf(fsub(py, fmul(0.5f, ph)), 0.0f), hi);
        float bx2 = fminf(fmaxf(fadd(px, fmul(0.5f, pw)), 0.0f), hi);
        float by2 = fminf(fmaxf(fadd(py, fmul(0.5f, ph)), 0.0f), hi);
        boxes[n*4+0]=bx1; boxes[n*4+1]=by1; boxes[n*4+2]=bx2; boxes[n*4+3]=by2;
        score[n] = sc;
        cls[n]   = c;
        key[n]   = valid ? sc : ninf;
    }
}

// K2: stable descending rank sort + nValid.
__global__ __launch_bounds__(256) void k_rank(
    const float* __restrict__ key, const float* __restrict__ boxes,
    float* __restrict__ boxesSorted, float* __restrict__ areaSorted,
    float* __restrict__ keySorted, int* __restrict__ rank,
    int* __restrict__ nValidPtr, int N)
{
    extern __shared__ float lkey[];
    __shared__ int part[256];
    int tid = threadIdx.x;
    for (int j = tid; j < N; j += 256) lkey[j] = key[j];
    __syncthreads();

    int i = blockIdx.x * 64 + (tid & 63);
    int s = tid >> 6;
    int Q = (N + 3) >> 2;
    int r_part = 0;
    if (i < N) {
        float ki = lkey[i];
        int j0 = s * Q, j1 = min(N, j0 + Q);
        for (int j = j0; j < j1; ++j) {
            float kj = lkey[j];
            r_part += (kj > ki) || (kj == ki && j < i);
        }
    }
    part[tid] = r_part;
    __syncthreads();

    if (tid < 64 && i < N) {
        int r = part[tid] + part[tid+64] + part[tid+128] + part[tid+192];
        float ki = lkey[i];
        rank[i] = r;
        float b0 = boxes[i*4+0], b1 = boxes[i*4+1], b2 = boxes[i*4+2], b3 = boxes[i*4+3];
        boxesSorted[r*4+0]=b0; boxesSorted[r*4+1]=b1; boxesSorted[r*4+2]=b2; boxesSorted[r*4+3]=b3;
        areaSorted[r] = fmul(fsub(b2,b0), fsub(b3,b1));
        keySorted[r]  = ki;
    }

    if (blockIdx.x == 0) {
        __syncthreads();
        float ninf = -__builtin_inff();
        int inv = 0;
        for (int j = tid; j < N; j += 256) inv += (lkey[j] == ninf);
        part[tid] = inv;
        __syncthreads();
        if (tid == 0) {
            int t = 0;
            for (int q = 0; q < 256; ++q) t += part[q];
            nValidPtr[0] = N - t;
        }
    }
}

// K3: suppression bitmask, row-major padded. dq[i*4+d] = forward word
// (i>>6)+d of row i. NEW: backward masks (IoU symmetric):
//   bdiag[i] = bits k<(i&63): IoU(row (i&~63)+k, i) > thr   (own word)
//   bprev[i] = bits k: IoU(row (i&~63)-64+k, i) > thr        (prev word;
//              only written when (i>>6) is odd — chunk-internal use only)
__global__ __launch_bounds__(256) void k_mask(
    const float* __restrict__ bs, const float* __restrict__ areas,
    const float* __restrict__ keySorted, unsigned long long* __restrict__ mask,
    unsigned long long* __restrict__ dq,
    unsigned long long* __restrict__ bdiag, unsigned long long* __restrict__ bprev,
    int N, int W, int Wpad)
{
    int wid  = threadIdx.x >> 6;
    int lane = threadIdx.x & 63;
    int i = blockIdx.x * 4 + wid;
    if (i >= N) return;
    if (keySorted[i] == -__builtin_inff()) return;
    float ax1 = bs[i*4+0], ay1 = bs[i*4+1], ax2 = bs[i*4+2], ay2 = bs[i*4+3];
    float aa  = areas[i];
    int w0 = i >> 6;
    if (lane == 0) {
        dq[i*4+0] = 0ULL; dq[i*4+1] = 0ULL; dq[i*4+2] = 0ULL; dq[i*4+3] = 0ULL;
    }
    // backward word from previous 64-word (chunk-internal: only odd w0)
    if (w0 & 1) {
        int j = (w0 - 1) * 64 + lane;       // all j < i
        int bit = 0;
        if (j < N) {
            float bx1 = bs[j*4+0], by1 = bs[j*4+1], bx2 = bs[j*4+2], by2 = bs[j*4+3];
            float ba  = areas[j];
            float ix1 = fmaxf(ax1,bx1), iy1 = fmaxf(ay1,by1);
            float ix2 = fminf(ax2,bx2), iy2 = fminf(ay2,by2);
            float iw = fmaxf(fsub(ix2,ix1), 0.0f);
            float ih = fmaxf(fsub(iy2,iy1), 0.0f);
            float inter = fmul(iw, ih);
            float denom = fadd(fsub(fadd(aa, ba), inter), 1e-9f);
            float iou = inter / denom;
            bit = (iou > NMS_THR) ? 1 : 0;
        }
        unsigned long long bm = __ballot(bit);
        if (lane == 0) bprev[i] = bm;
    }
    for (int w = w0; w < W; ++w) {
        int j = w*64 + lane;
        int bit = 0;
        if (j < N && j != i) {
            float bx1 = bs[j*4+0], by1 = bs[j*4+1], bx2 = bs[j*4+2], by2 = bs[j*4+3];
            float ba  = areas[j];
            float ix1 = fmaxf(ax1,bx1), iy1 = fmaxf(ay1,by1);
            float ix2 = fminf(ax2,bx2), iy2 = fminf(ay2,by2);
            float iw = fmaxf(fsub(ix2,ix1), 0.0f);
            float ih = fmaxf(fsub(iy2,iy1), 0.0f);
            float inter = fmul(iw, ih);
            float denom = fadd(fsub(fadd(aa, ba), inter), 1e-9f);
            float iou = inter / denom;
            bit = (iou > NMS_THR) ? 1 : 0;
        }
        unsigned long long fwd = __ballot(bit && (j > i));
        if (w == w0) {
            unsigned long long bwd = __ballot(bit && (j < i));
            if (lane == 0) {
                mask[(long)i*Wpad + w] = fwd;
                dq[i*4+0] = fwd;
                bdiag[i]  = bwd;
            }
        } else {
            if (lane == 0) {
                mask[(long)i*Wpad + w] = fwd;
                int d = w - w0;
                if (d < 4) dq[i*4+d] = fwd;
            }
        }
    }
}

// K4: wave-specialized greedy scan, 128-row chunks. Resolver keep-chain uses
// BACKWARD masks: lane L holds its own rows' suppressor bits, so each keep is
// {ctz(uniform cand) -> broadcast bit-test -> ballot -> andn2} — ZERO
// readlanes. Cross-phase suppression = one ballot(vBp & keepLo). sacc via
// lane-mask cndmask + waveOr (R12). Acc waves identical to R12.
__global__ __launch_bounds__((NACC+1)*64, 1) void k_scan(
    const unsigned long long* __restrict__ mask,
    const unsigned long long* __restrict__ dq,
    const unsigned long long* __restrict__ bdiag,
    const unsigned long long* __restrict__ bprev,
    const int* __restrict__ nValidPtr,
    int* __restrict__ keepSorted, int N, int W, int Wpad)
{
    __shared__ unsigned long long ldsPartA[NACC+1];
    __shared__ unsigned long long ldsPartB[NACC+1];
    __shared__ unsigned long long ldsKeepLo, ldsKeepHi;
    int tid  = threadIdx.x;
    int wid  = tid >> 6;
    int lane = tid & 63;
    for (int i = tid; i < N; i += (NACC+1)*64) keepSorted[i] = 0;
    if (tid <= NACC) { ldsPartA[tid] = 0ULL; ldsPartB[tid] = 0ULL; }
    if (tid == 0) { ldsKeepLo = 0ULL; ldsKeepHi = 0ULL; }
    __syncthreads();

    int nValid  = __builtin_amdgcn_readfirstlane(nValidPtr[0]);
    int nChunks = (nValid + 127) >> 7;

    // resolver state: backward masks + sacc forward words for current chunk
    unsigned long long vA=0, vBp=0, vBd=0, A2=0, A3=0, B1=0, B2=0;
    unsigned long long sacc_prevA = 0ULL, sacc_prevB = 0ULL;
    if (wid == 0 && nChunks > 0) {
        int rA = lane, rB = 64 + lane;
        if (rA < N) {
            vA = bdiag[rA];
            ulonglong2 a23 = *(const ulonglong2*)(dq + (size_t)rA*4 + 2);
            A2 = a23.x; A3 = a23.y;
        }
        if (rB < N) {
            vBp = bprev[rB];
            vBd = bdiag[rB];
            ulonglong2 b01 = *(const ulonglong2*)(dq + (size_t)rB*4);
            ulonglong2 b23 = *(const ulonglong2*)(dq + (size_t)rB*4 + 2);
            B1 = b01.y; B2 = b23.x;
        }
    }
    unsigned long long accx = 0ULL, accy = 0ULL;
    bool accWave = (wid >= 1);
    int  accIdx  = wid - 1;
    bool laneok  = (2*lane + 1 < Wpad);

    for (int c = 0; c < nChunks; ++c) {
        int base = c << 7;
        if (wid == 0) {
            // prefetch next chunk (vmem stays in flight across BAR_LDS)
            unsigned long long nvA=0, nvBp=0, nvBd=0, nA2=0, nA3=0, nB1=0, nB2=0;
            if (c + 1 < nChunks) {
                int rA = base + 128 + lane, rB = base + 192 + lane;
                if (rA < N) {
                    nvA = bdiag[rA];
                    ulonglong2 a23 = *(const ulonglong2*)(dq + (size_t)rA*4 + 2);
                    nA2 = a23.x; nA3 = a23.y;
                }
                if (rB < N) {
                    nvBp = bprev[rB];
                    nvBd = bdiag[rB];
                    ulonglong2 b01 = *(const ulonglong2*)(dq + (size_t)rB*4);
                    ulonglong2 b23 = *(const ulonglong2*)(dq + (size_t)rB*4 + 2);
                    nB1 = b01.y; nB2 = b23.x;
                }
            }

            unsigned long long pA = sacc_prevA, pB = sacc_prevB;
#pragma unroll
            for (int k = 1; k <= NACC; ++k) { pA |= ldsPartA[k]; pB |= ldsPartB[k]; }
            unsigned long long incLo = rfl64(pA), incHi = rfl64(pB);
            int nv  = nValid - base;
            unsigned long long validLo = (nv >= 64) ? ~0ULL : ((1ULL << nv) - 1ULL);
            int nv2 = nv - 64;
            unsigned long long validHi = (nv2 >= 64) ? ~0ULL
                                        : (nv2 <= 0 ? 0ULL : ((1ULL << nv2) - 1ULL));
            unsigned long long candLo = validLo & ~incLo;
            unsigned long long candHi = validHi & ~incHi;
            unsigned long long keepLo = 0ULL, keepHi = 0ULL;

            // phase 1: rows base..base+63 — broadcast-test chain, no readlanes
            while (candLo) {
                int f = __builtin_ctzll(candLo);
                unsigned long long sup = __ballot(((vA >> f) & 1ULL) != 0ULL);
                unsigned long long b = 1ULL << f;
                keepLo |= b;
                candLo &= ~sup & ~b;
            }
            // phase-1 keeps suppress second half: one ballot
            candHi &= ~__ballot((vBp & keepLo) != 0ULL);
            // phase 2: rows base+64..base+127
            while (candHi) {
                int f = __builtin_ctzll(candHi);
                unsigned long long sup = __ballot(((vBd >> f) & 1ULL) != 0ULL);
                unsigned long long b = 1ULL << f;
                keepHi |= b;
                candHi &= ~sup & ~b;
            }
            // sacc: forward words of kept rows (lane-mask select + wave OR)
            {
                unsigned long long kL = (keepLo >> lane) & 1ULL;
                unsigned long long kH = (keepHi >> lane) & 1ULL;
                unsigned long long selA = (kL ? A2 : 0ULL) | (kH ? B1 : 0ULL);
                unsigned long long selB = (kL ? A3 : 0ULL) | (kH ? B2 : 0ULL);
                sacc_prevA = waveOr64(selA);
                sacc_prevB = waveOr64(selB);
            }
            if (lane == 0) { ldsKeepLo = keepLo; ldsKeepHi = keepHi; }
            if (base + lane < N)      keepSorted[base + lane]      = (int)((keepLo >> lane) & 1ULL);
            if (base + 64 + lane < N) keepSorted[base + 64 + lane] = (int)((keepHi >> lane) & 1ULL);
            vA=nvA; vBp=nvBp; vBd=nvBd; A2=nA2; A3=nA3; B1=nB1; B2=nB2;
        }
        BAR_LDS();                             // barrier A
        unsigned long long kLo = ldsKeepLo;
        unsigned long long kHi = ldsKeepHi;
        if (accWave && laneok && lane == c + 1) {  // publish words 2c+2, 2c+3
            ldsPartA[wid] = accx;
            ldsPartB[wid] = accy;
        }
        BAR_LDS();                             // barrier B
        if (accWave && laneok) {
            unsigned int myb = (accIdx < 4)
                ? (unsigned int)((kLo >> (16*accIdx)) & 0xFFFFULL)
                : (unsigned int)((kHi >> (16*(accIdx-4))) & 0xFFFFULL);
            if (myb) {
                const unsigned long long* mb =
                    mask + (size_t)(base + 16*accIdx) * Wpad + 2*lane;
                unsigned int b = myb;
                int a0 = __builtin_ctz(b); b &= b - 1;
                int a1=-1,a2=-1,a3=-1,a4=-1,a5=-1,a6=-1,a7=-1;
                if (b) { a1 = __builtin_ctz(b); b &= b - 1; }
                if (b) { a2 = __builtin_ctz(b); b &= b - 1; }
                if (b) { a3 = __builtin_ctz(b); b &= b - 1; }
                if (b) { a4 = __builtin_ctz(b); b &= b - 1; }
                if (b) { a5 = __builtin_ctz(b); b &= b - 1; }
                if (b) { a6 = __builtin_ctz(b); b &= b - 1; }
                if (b) { a7 = __builtin_ctz(b); b &= b - 1; }
                ulonglong2 v0 = {0,0}, v1 = {0,0}, v2 = {0,0}, v3 = {0,0};
                ulonglong2 v4 = {0,0}, v5 = {0,0}, v6 = {0,0}, v7 = {0,0};
                v0 = *(const ulonglong2*)(mb + (size_t)a0 * Wpad);
                if (a1 >= 0) v1 = *(const ulonglong2*)(mb + (size_t)a1 * Wpad);
                if (a2 >= 0) v2 = *(const ulonglong2*)(mb + (size_t)a2 * Wpad);
                if (a3 >= 0) v3 = *(const ulonglong2*)(mb + (size_t)a3 * Wpad);
                if (a4 >= 0) v4 = *(const ulonglong2*)(mb + (size_t)a4 * Wpad);
                if (a5 >= 0) v5 = *(const ulonglong2*)(mb + (size_t)a5 * Wpad);
                if (a6 >= 0) v6 = *(const ulonglong2*)(mb + (size_t)a6 * Wpad);
                if (a7 >= 0) v7 = *(const ulonglong2*)(mb + (size_t)a7 * Wpad);
                accx |= ((v0.x|v1.x)|(v2.x|v3.x)) | ((v4.x|v5.x)|(v6.x|v7.x));
                accy |= ((v0.y|v1.y)|(v2.y|v3.y)) | ((v4.y|v5.y)|(v6.y|v7.y));
                while (b) {
                    int a = __builtin_ctz(b); b &= b - 1;
                    ulonglong2 v = *(const ulonglong2*)(mb + (size_t)a * Wpad);
                    accx |= v.x; accy |= v.y;
                }
            }
        }
    }
}

// K5: write outputs in original order: boxes*m, score*m, float(cls*keep).
__global__ __launch_bounds__(256) void k_out(
    const float* __restrict__ boxes, const float* __restrict__ score,
    const int* __restrict__ cls, const int* __restrict__ rank,
    const int* __restrict__ keepSorted,
    float* __restrict__ out, int N)
{
    int n = blockIdx.x * blockDim.x + threadIdx.x;
    if (n >= N) return;
    int k = keepSorted[rank[n]];
    float m = (float)k;
    out[n*4+0] = boxes[n*4+0]*m;
    out[n*4+1] = boxes[n*4+1]*m;
    out[n*4+2] = boxes[n*4+2]*m;
    out[n*4+3] = boxes[n*4+3]*m;
    out[(long)N*4 + n] = score[n]*m;
    out[(long)N*5 + n] = (float)(cls[n] * k);
}

extern "C" void kernel_launch(void* const* d_in, const int* in_sizes, int n_in,
                              void* d_out, int out_size, void* d_ws, size_t ws_size,
                              hipStream_t stream) {
    const float* prop = (const float*)d_in[0];
    const float* reg  = (const float*)d_in[1];
    const float* clss = (const float*)d_in[2];
    const float* stds = (const float*)d_in[3];
    const int*   img  = (const int*)d_in[4];

    int N = in_sizes[0] / 4;
    int C = in_sizes[2] / N;
    int W = (N + 63) / 64;
    int Wpad = (W + 1) & ~1;

    char* ws = (char*)d_ws;
    size_t off = 0;
    float* boxes       = (float*)(ws + off); off += (size_t)N*4*sizeof(float);
    float* key         = (float*)(ws + off); off += (size_t)N*sizeof(float);
    float* score       = (float*)(ws + off); off += (size_t)N*sizeof(float);
    int*   cls         = (int*)  (ws + off); off += (size_t)N*sizeof(int);
    int*   rank        = (int*)  (ws + off); off += (size_t)N*sizeof(int);
    float* boxesSorted = (float*)(ws + off); off += (size_t)N*4*sizeof(float);
    float* areaSorted  = (float*)(ws + off); off += (size_t)N*sizeof(float);
    float* keySorted   = (float*)(ws + off); off += (size_t)N*sizeof(float);
    int*   keepSorted  = (int*)  (ws + off); off += (size_t)N*sizeof(int);
    int*   nValid      = (int*)  (ws + off); off += sizeof(int);
    off = (off + 31) & ~(size_t)31;
    unsigned long long* dq    = (unsigned long long*)(ws + off);
    off += (size_t)N * 4 * sizeof(unsigned long long);
    unsigned long long* bdiag = (unsigned long long*)(ws + off);
    off += (size_t)N * sizeof(unsigned long long);
    unsigned long long* bprev = (unsigned long long*)(ws + off);
    off += (size_t)N * sizeof(unsigned long long);
    unsigned long long* mask  = (unsigned long long*)(ws + off);
    off += (size_t)N * Wpad * sizeof(unsigned long long);
    (void)ws_size; (void)out_size; (void)n_in;

    int rowBlocks  = (N + 3) / 4;
    int thrBlocks  = (N + 255) / 256;
    int rankBlocks = (N + 63) / 64;

    k_decode<<<rowBlocks, 256, 0, stream>>>(prop, reg, clss, stds, img,
                                            boxes, key, score, cls, N, C);
    k_rank<<<rankBlocks, 256, (size_t)N*sizeof(float), stream>>>(key, boxes,
                                            boxesSorted, areaSorted, keySorted, rank, nValid, N);
    k_mask<<<rowBlocks, 256, 0, stream>>>(boxesSorted, areaSorted, keySorted,
                                          mask, dq, bdiag, bprev, N, W, Wpad);
    k_scan<<<1, (NACC+1)*64, 0, stream>>>(mask, dq, bdiag, bprev, nValid,
                                          keepSorted, N, W, Wpad);
    k_out<<<thrBlocks, 256, 0, stream>>>(boxes, score, cls, rank, keepSorted,
                                         (float*)d_out, N);
}

// Round 17
// 170.613 us; speedup vs baseline: 6.1630x; 1.0608x over previous
//
#include <hip/hip_runtime.h>
#include <math.h>

#define NMS_THR 0.3f
#define NACC 8   // accumulator waves in k_scan (block = (1+NACC)*64 threads)

__device__ __forceinline__ float fmul(float a, float b){ return __fmul_rn(a,b); }
__device__ __forceinline__ float fadd(float a, float b){ return __fadd_rn(a,b); }
__device__ __forceinline__ float fsub(float a, float b){ return __fsub_rn(a,b); }

// Raw barrier: LDS ordering only — does NOT drain vmcnt.
#define BAR_LDS() asm volatile("s_waitcnt lgkmcnt(0)\n\ts_barrier" ::: "memory")

__device__ __forceinline__ unsigned long long rfl64(unsigned long long x){
    unsigned int lo = (unsigned int)__builtin_amdgcn_readfirstlane((int)(unsigned int)x);
    unsigned int hi = (unsigned int)__builtin_amdgcn_readfirstlane((int)(unsigned int)(x >> 32));
    return ((unsigned long long)hi << 32) | lo;
}

// K1: per-row softmax max/sum + argmax + per-class regression decode.
__global__ __launch_bounds__(256) void k_decode(
    const float* __restrict__ prop, const float* __restrict__ reg,
    const float* __restrict__ clss, const float* __restrict__ stds,
    const int* __restrict__ imgsz,
    float* __restrict__ boxes, float* __restrict__ key,
    float* __restrict__ score, int* __restrict__ cls,
    int N, int C)
{
    int wid  = threadIdx.x >> 6;
    int lane = threadIdx.x & 63;
    int n = blockIdx.x * 4 + wid;
    if (n >= N) return;
    const float* row = clss + (long)n * C;
    float ninf = -__builtin_inff();
    float x0 = (lane < C)      ? row[lane]      : ninf;
    float x1 = (lane + 64 < C) ? row[lane + 64] : ninf;
    float m = fmaxf(x0, x1);
    for (int o = 32; o > 0; o >>= 1) m = fmaxf(m, __shfl_xor(m, o));
    float e0 = (lane < C)      ? expf(x0 - m) : 0.0f;
    float e1 = (lane + 64 < C) ? expf(x1 - m) : 0.0f;
    float s = e0 + e1;
    for (int o = 32; o > 0; o >>= 1) s += __shfl_xor(s, o);
    float bv; int bi;
    if (e0 >= e1) { bv = e0; bi = lane; } else { bv = e1; bi = lane + 64; }
    for (int o = 32; o > 0; o >>= 1) {
        float ov = __shfl_xor(bv, o);
        int   oi = __shfl_xor(bi, o);
        if (ov > bv || (ov == bv && oi < bi)) { bv = ov; bi = oi; }
    }
    if (lane == 0) {
        float sc = 1.0f / s;
        int   c  = bi;
        int   valid = (c != 0);
        float p0 = prop[n*4+0], p1 = prop[n*4+1], p2 = prop[n*4+2], p3 = prop[n*4+3];
        float w  = fsub(p2, p0), h = fsub(p3, p1);
        float cx = fadd(p0, fmul(0.5f, w));
        float cy = fadd(p1, fmul(0.5f, h));
        const float* rr = reg + (long)n * C * 4 + (long)c * 4;
        float t0 = fmul(rr[0], stds[0]);
        float t1 = fmul(rr[1], stds[1]);
        float t2 = fmul(rr[2], stds[2]);
        float t3 = fmul(rr[3], stds[3]);
        float px = fadd(cx, fmul(w, t0));
        float py = fadd(cy, fmul(h, t1));
        float pw = fmul(w, expf(t2));
        float ph = fmul(h, expf(t3));
        float hi = (float)(imgsz[0] - 1);
        float bx1 = fminf(fmaxf(fsub(px, fmul(0.5f, pw)), 0.0f), hi);
        float by1 = fminf(fmaxf(fsub(py, fmul(0.5f, ph)), 0.0f), hi);
        float bx2 = fminf(fmaxf(fadd(px, fmul(0.5f, pw)), 0.0f), hi);
        float by2 = fminf(fmaxf(fadd(py, fmul(0.5f, ph)), 0.0f), hi);
        boxes[n*4+0]=bx1; boxes[n*4+1]=by1; boxes[n*4+2]=bx2; boxes[n*4+3]=by2;
        score[n] = sc;
        cls[n]   = c;
        key[n]   = valid ? sc : ninf;
    }
}

// K2: stable descending rank sort + nValid.
__global__ __launch_bounds__(256) void k_rank(
    const float* __restrict__ key, const float* __restrict__ boxes,
    float* __restrict__ boxesSorted, float* __restrict__ areaSorted,
    float* __restrict__ keySorted, int* __restrict__ rank,
    int* __restrict__ nValidPtr, int N)
{
    extern __shared__ float lkey[];
    __shared__ int part[256];
    int tid = threadIdx.x;
    for (int j = tid; j < N; j += 256) lkey[j] = key[j];
    __syncthreads();

    int i = blockIdx.x * 64 + (tid & 63);
    int s = tid >> 6;
    int Q = (N + 3) >> 2;
    int r_part = 0;
    if (i < N) {
        float ki = lkey[i];
        int j0 = s * Q, j1 = min(N, j0 + Q);
        for (int j = j0; j < j1; ++j) {
            float kj = lkey[j];
            r_part += (kj > ki) || (kj == ki && j < i);
        }
    }
    part[tid] = r_part;
    __syncthreads();

    if (tid < 64 && i < N) {
        int r = part[tid] + part[tid+64] + part[tid+128] + part[tid+192];
        float ki = lkey[i];
        rank[i] = r;
        float b0 = boxes[i*4+0], b1 = boxes[i*4+1], b2 = boxes[i*4+2], b3 = boxes[i*4+3];
        boxesSorted[r*4+0]=b0; boxesSorted[r*4+1]=b1; boxesSorted[r*4+2]=b2; boxesSorted[r*4+3]=b3;
        areaSorted[r] = fmul(fsub(b2,b0), fsub(b3,b1));
        keySorted[r]  = ki;
    }

    if (blockIdx.x == 0) {
        __syncthreads();
        float ninf = -__builtin_inff();
        int inv = 0;
        for (int j = tid; j < N; j += 256) inv += (lkey[j] == ninf);
        part[tid] = inv;
        __syncthreads();
        if (tid == 0) {
            int t = 0;
            for (int q = 0; q < 256; ++q) t += part[q];
            nValidPtr[0] = N - t;
        }
    }
}

// K3: suppression bitmask, row-major padded (forward rows for acc waves), plus
// per-row BACKWARD quad bq[i*4+k]:
//   k=0: bits j<(i&63) in own word w0 with IoU>thr
//   k=1..3: bits j in word w0-k with IoU>thr (0 if w0-k < 0)
// (IoU symmetric; all j in these words are < i.)
__global__ __launch_bounds__(256) void k_mask(
    const float* __restrict__ bs, const float* __restrict__ areas,
    const float* __restrict__ keySorted, unsigned long long* __restrict__ mask,
    unsigned long long* __restrict__ bq,
    int N, int W, int Wpad)
{
    int wid  = threadIdx.x >> 6;
    int lane = threadIdx.x & 63;
    int i = blockIdx.x * 4 + wid;
    if (i >= N) return;
    if (keySorted[i] == -__builtin_inff()) return;   // invalid rows never read
    float ax1 = bs[i*4+0], ay1 = bs[i*4+1], ax2 = bs[i*4+2], ay2 = bs[i*4+3];
    float aa  = areas[i];
    int w0 = i >> 6;
    // backward words k=1..3
#pragma unroll
    for (int k = 1; k <= 3; ++k) {
        unsigned long long bm = 0ULL;
        if (w0 - k >= 0) {
            int j = (w0 - k) * 64 + lane;    // j < i always
            float bx1 = bs[j*4+0], by1 = bs[j*4+1], bx2 = bs[j*4+2], by2 = bs[j*4+3];
            float ba  = areas[j];
            float ix1 = fmaxf(ax1,bx1), iy1 = fmaxf(ay1,by1);
            float ix2 = fminf(ax2,bx2), iy2 = fminf(ay2,by2);
            float iw = fmaxf(fsub(ix2,ix1), 0.0f);
            float ih = fmaxf(fsub(iy2,iy1), 0.0f);
            float inter = fmul(iw, ih);
            float denom = fadd(fsub(fadd(aa, ba), inter), 1e-9f);
            float iou = inter / denom;
            bm = __ballot(iou > NMS_THR);
        }
        if (lane == 0) bq[(size_t)i*4 + k] = bm;
    }
    // forward words + own-word backward
    for (int w = w0; w < W; ++w) {
        int j = w*64 + lane;
        int bit = 0;
        if (j < N && j != i) {
            float bx1 = bs[j*4+0], by1 = bs[j*4+1], bx2 = bs[j*4+2], by2 = bs[j*4+3];
            float ba  = areas[j];
            float ix1 = fmaxf(ax1,bx1), iy1 = fmaxf(ay1,by1);
            float ix2 = fminf(ax2,bx2), iy2 = fminf(ay2,by2);
            float iw = fmaxf(fsub(ix2,ix1), 0.0f);
            float ih = fmaxf(fsub(iy2,iy1), 0.0f);
            float inter = fmul(iw, ih);
            float denom = fadd(fsub(fadd(aa, ba), inter), 1e-9f);
            float iou = inter / denom;
            bit = (iou > NMS_THR) ? 1 : 0;
        }
        unsigned long long fwd = __ballot(bit && (j > i));
        if (w == w0) {
            unsigned long long bwd = __ballot(bit && (j < i));
            if (lane == 0) {
                mask[(long)i*Wpad + w] = fwd;
                bq[(size_t)i*4 + 0] = bwd;
            }
        } else {
            if (lane == 0) mask[(long)i*Wpad + w] = fwd;
        }
    }
}

// K4: wave-specialized greedy scan, 128-row chunks. Resolver is all
// backward-mask ballots: keep chain = {ctz -> broadcast bit-test -> ballot ->
// andn2}; prev-chunk suppression = 2 ballots on bq1..bq3 vs prev keep words
// (replaces the waveOr64 sacc machinery + dq loads). ldsPart covers chunks
// <= c-2 (lag-1 acc publish, unchanged). Acc waves identical to R12.
__global__ __launch_bounds__((NACC+1)*64, 1) void k_scan(
    const unsigned long long* __restrict__ mask,
    const unsigned long long* __restrict__ bq,
    const int* __restrict__ nValidPtr,
    int* __restrict__ keepSorted, int N, int W, int Wpad)
{
    __shared__ unsigned long long ldsPartA[NACC+1];
    __shared__ unsigned long long ldsPartB[NACC+1];
    __shared__ unsigned long long ldsKeepLo, ldsKeepHi;
    int tid  = threadIdx.x;
    int wid  = tid >> 6;
    int lane = tid & 63;
    for (int i = tid; i < N; i += (NACC+1)*64) keepSorted[i] = 0;
    if (tid <= NACC) { ldsPartA[tid] = 0ULL; ldsPartB[tid] = 0ULL; }
    if (tid == 0) { ldsKeepLo = 0ULL; ldsKeepHi = 0ULL; }
    __syncthreads();

    int nValid  = __builtin_amdgcn_readfirstlane(nValidPtr[0]);
    int nChunks = (nValid + 127) >> 7;

    // resolver state: backward quads for current chunk rows
    unsigned long long a0=0,a1=0,a2=0,a3=0, b0=0,b1=0,b2=0,b3=0;
    unsigned long long keepLoPrev = 0ULL, keepHiPrev = 0ULL;
    if (wid == 0 && nChunks > 0) {
        int rA = lane, rB = 64 + lane;
        if (rA < N) {
            ulonglong2 q01 = *(const ulonglong2*)(bq + (size_t)rA*4);
            ulonglong2 q23 = *(const ulonglong2*)(bq + (size_t)rA*4 + 2);
            a0=q01.x; a1=q01.y; a2=q23.x; a3=q23.y;
        }
        if (rB < N) {
            ulonglong2 q01 = *(const ulonglong2*)(bq + (size_t)rB*4);
            ulonglong2 q23 = *(const ulonglong2*)(bq + (size_t)rB*4 + 2);
            b0=q01.x; b1=q01.y; b2=q23.x; b3=q23.y;
        }
    }
    unsigned long long accx = 0ULL, accy = 0ULL;
    bool accWave = (wid >= 1);
    int  accIdx  = wid - 1;
    bool laneok  = (2*lane + 1 < Wpad);

    for (int c = 0; c < nChunks; ++c) {
        int base = c << 7;
        if (wid == 0) {
            // prefetch next chunk's quads (vmem stays in flight across BAR_LDS)
            unsigned long long na0=0,na1=0,na2=0,na3=0, nb0=0,nb1=0,nb2=0,nb3=0;
            if (c + 1 < nChunks) {
                int rA = base + 128 + lane, rB = base + 192 + lane;
                if (rA < N) {
                    ulonglong2 q01 = *(const ulonglong2*)(bq + (size_t)rA*4);
                    ulonglong2 q23 = *(const ulonglong2*)(bq + (size_t)rA*4 + 2);
                    na0=q01.x; na1=q01.y; na2=q23.x; na3=q23.y;
                }
                if (rB < N) {
                    ulonglong2 q01 = *(const ulonglong2*)(bq + (size_t)rB*4);
                    ulonglong2 q23 = *(const ulonglong2*)(bq + (size_t)rB*4 + 2);
                    nb0=q01.x; nb1=q01.y; nb2=q23.x; nb3=q23.y;
                }
            }

            // inc: acc partials (chunks <= c-2) + prev-chunk ballots (chunk c-1)
            unsigned long long pA = 0ULL, pB = 0ULL;
#pragma unroll
            for (int k = 1; k <= NACC; ++k) { pA |= ldsPartA[k]; pB |= ldsPartB[k]; }
            unsigned long long prevLo =
                __ballot(((a1 & keepHiPrev) | (a2 & keepLoPrev)) != 0ULL);
            unsigned long long prevHi =
                __ballot(((b2 & keepHiPrev) | (b3 & keepLoPrev)) != 0ULL);
            unsigned long long incLo = rfl64(pA) | prevLo;
            unsigned long long incHi = rfl64(pB) | prevHi;
            int nv  = nValid - base;
            unsigned long long validLo = (nv >= 64) ? ~0ULL : ((1ULL << nv) - 1ULL);
            int nv2 = nv - 64;
            unsigned long long validHi = (nv2 >= 64) ? ~0ULL
                                        : (nv2 <= 0 ? 0ULL : ((1ULL << nv2) - 1ULL));
            unsigned long long candLo = validLo & ~incLo;
            unsigned long long candHi = validHi & ~incHi;
            unsigned long long keepLo = 0ULL, keepHi = 0ULL;

            // phase 1: rows base..base+63 — broadcast-test chain
            while (candLo) {
                int f = __builtin_ctzll(candLo);
                unsigned long long sup = __ballot(((a0 >> f) & 1ULL) != 0ULL);
                unsigned long long b = 1ULL << f;
                keepLo |= b;
                candLo &= ~sup & ~b;
            }
            // phase-1 keeps suppress second half: one ballot (b1 = word 2c)
            candHi &= ~__ballot((b1 & keepLo) != 0ULL);
            // phase 2: rows base+64..base+127
            while (candHi) {
                int f = __builtin_ctzll(candHi);
                unsigned long long sup = __ballot(((b0 >> f) & 1ULL) != 0ULL);
                unsigned long long b = 1ULL << f;
                keepHi |= b;
                candHi &= ~sup & ~b;
            }
            keepLoPrev = keepLo; keepHiPrev = keepHi;
            if (lane == 0) { ldsKeepLo = keepLo; ldsKeepHi = keepHi; }
            if (base + lane < N)      keepSorted[base + lane]      = (int)((keepLo >> lane) & 1ULL);
            if (base + 64 + lane < N) keepSorted[base + 64 + lane] = (int)((keepHi >> lane) & 1ULL);
            a0=na0; a1=na1; a2=na2; a3=na3; b0=nb0; b1=nb1; b2=nb2; b3=nb3;
        }
        BAR_LDS();                             // barrier A
        unsigned long long kLo = ldsKeepLo;
        unsigned long long kHi = ldsKeepHi;
        if (accWave && laneok && lane == c + 1) {  // publish words 2c+2, 2c+3
            ldsPartA[wid] = accx;
            ldsPartB[wid] = accy;
        }
        BAR_LDS();                             // barrier B
        if (accWave && laneok) {
            unsigned int myb = (accIdx < 4)
                ? (unsigned int)((kLo >> (16*accIdx)) & 0xFFFFULL)
                : (unsigned int)((kHi >> (16*(accIdx-4))) & 0xFFFFULL);
            if (myb) {
                const unsigned long long* mb =
                    mask + (size_t)(base + 16*accIdx) * Wpad + 2*lane;
                unsigned int b = myb;
                int q0 = __builtin_ctz(b); b &= b - 1;
                int q1=-1,q2=-1,q3=-1,q4=-1,q5=-1,q6=-1,q7=-1;
                if (b) { q1 = __builtin_ctz(b); b &= b - 1; }
                if (b) { q2 = __builtin_ctz(b); b &= b - 1; }
                if (b) { q3 = __builtin_ctz(b); b &= b - 1; }
                if (b) { q4 = __builtin_ctz(b); b &= b - 1; }
                if (b) { q5 = __builtin_ctz(b); b &= b - 1; }
                if (b) { q6 = __builtin_ctz(b); b &= b - 1; }
                if (b) { q7 = __builtin_ctz(b); b &= b - 1; }
                ulonglong2 v0 = {0,0}, v1 = {0,0}, v2 = {0,0}, v3 = {0,0};
                ulonglong2 v4 = {0,0}, v5 = {0,0}, v6 = {0,0}, v7 = {0,0};
                v0 = *(const ulonglong2*)(mb + (size_t)q0 * Wpad);
                if (q1 >= 0) v1 = *(const ulonglong2*)(mb + (size_t)q1 * Wpad);
                if (q2 >= 0) v2 = *(const ulonglong2*)(mb + (size_t)q2 * Wpad);
                if (q3 >= 0) v3 = *(const ulonglong2*)(mb + (size_t)q3 * Wpad);
                if (q4 >= 0) v4 = *(const ulonglong2*)(mb + (size_t)q4 * Wpad);
                if (q5 >= 0) v5 = *(const ulonglong2*)(mb + (size_t)q5 * Wpad);
                if (q6 >= 0) v6 = *(const ulonglong2*)(mb + (size_t)q6 * Wpad);
                if (q7 >= 0) v7 = *(const ulonglong2*)(mb + (size_t)q7 * Wpad);
                accx |= ((v0.x|v1.x)|(v2.x|v3.x)) | ((v4.x|v5.x)|(v6.x|v7.x));
                accy |= ((v0.y|v1.y)|(v2.y|v3.y)) | ((v4.y|v5.y)|(v6.y|v7.y));
                while (b) {
                    int a = __builtin_ctz(b); b &= b - 1;
                    ulonglong2 v = *(const ulonglong2*)(mb + (size_t)a * Wpad);
                    accx |= v.x; accy |= v.y;
                }
            }
        }
    }
}

// K5: write outputs in original order: boxes*m, score*m, float(cls*keep).
__global__ __launch_bounds__(256) void k_out(
    const float* __restrict__ boxes, const float* __restrict__ score,
    const int* __restrict__ cls, const int* __restrict__ rank,
    const int* __restrict__ keepSorted,
    float* __restrict__ out, int N)
{
    int n = blockIdx.x * blockDim.x + threadIdx.x;
    if (n >= N) return;
    int k = keepSorted[rank[n]];
    float m = (float)k;
    out[n*4+0] = boxes[n*4+0]*m;
    out[n*4+1] = boxes[n*4+1]*m;
    out[n*4+2] = boxes[n*4+2]*m;
    out[n*4+3] = boxes[n*4+3]*m;
    out[(long)N*4 + n] = score[n]*m;
    out[(long)N*5 + n] = (float)(cls[n] * k);
}

extern "C" void kernel_launch(void* const* d_in, const int* in_sizes, int n_in,
                              void* d_out, int out_size, void* d_ws, size_t ws_size,
                              hipStream_t stream) {
    const float* prop = (const float*)d_in[0];
    const float* reg  = (const float*)d_in[1];
    const float* clss = (const float*)d_in[2];
    const float* stds = (const float*)d_in[3];
    const int*   img  = (const int*)d_in[4];

    int N = in_sizes[0] / 4;
    int C = in_sizes[2] / N;
    int W = (N + 63) / 64;
    int Wpad = (W + 1) & ~1;

    char* ws = (char*)d_ws;
    size_t off = 0;
    float* boxes       = (float*)(ws + off); off += (size_t)N*4*sizeof(float);
    float* key         = (float*)(ws + off); off += (size_t)N*sizeof(float);
    float* score       = (float*)(ws + off); off += (size_t)N*sizeof(float);
    int*   cls         = (int*)  (ws + off); off += (size_t)N*sizeof(int);
    int*   rank        = (int*)  (ws + off); off += (size_t)N*sizeof(int);
    float* boxesSorted = (float*)(ws + off); off += (size_t)N*4*sizeof(float);
    float* areaSorted  = (float*)(ws + off); off += (size_t)N*sizeof(float);
    float* keySorted   = (float*)(ws + off); off += (size_t)N*sizeof(float);
    int*   keepSorted  = (int*)  (ws + off); off += (size_t)N*sizeof(int);
    int*   nValid      = (int*)  (ws + off); off += sizeof(int);
    off = (off + 31) & ~(size_t)31;
    unsigned long long* bq    = (unsigned long long*)(ws + off);
    off += (size_t)N * 4 * sizeof(unsigned long long);
    unsigned long long* mask  = (unsigned long long*)(ws + off);
    off += (size_t)N * Wpad * sizeof(unsigned long long);
    (void)ws_size; (void)out_size; (void)n_in;

    int rowBlocks  = (N + 3) / 4;
    int thrBlocks  = (N + 255) / 256;
    int rankBlocks = (N + 63) / 64;

    k_decode<<<rowBlocks, 256, 0, stream>>>(prop, reg, clss, stds, img,
                                            boxes, key, score, cls, N, C);
    k_rank<<<rankBlocks, 256, (size_t)N*sizeof(float), stream>>>(key, boxes,
                                            boxesSorted, areaSorted, keySorted, rank, nValid, N);
    k_mask<<<rowBlocks, 256, 0, stream>>>(boxesSorted, areaSorted, keySorted,
                                          mask, bq, N, W, Wpad);
    k_scan<<<1, (NACC+1)*64, 0, stream>>>(mask, bq, nValid, keepSorted, N, W, Wpad);
    k_out<<<thrBlocks, 256, 0, stream>>>(boxes, score, cls, rank, keepSorted,
                                         (float*)d_out, N);
}